// Round 4
// baseline (563.423 us; speedup 1.0000x reference)
//
#include <hip/hip_runtime.h>
#include <hip/hip_bf16.h>

typedef __attribute__((ext_vector_type(4))) float f32x4_t;
typedef __attribute__((ext_vector_type(8))) short bf16x8_t;

#define NCLS 8  // XCD count / partition classes

__device__ __forceinline__ float bf2f(ushort u) {
  return __uint_as_float(((unsigned)u) << 16);
}
__device__ __forceinline__ ushort f2bf(float f) {
  unsigned u = __float_as_uint(f);
  u += 0x7fffu + ((u >> 16) & 1u);
  return (ushort)(u >> 16);
}

// ---- histogram of dst, partitioned by class(i) = (i>>8)&7 ----
// Class j's counters live in deg2[j*N ..], a private 400KB region whose
// lines are only touched by XCD j (blocks round-robin over XCDs) -> atomics
// stay in the local L2, no cross-XCD line bouncing.
__global__ void deg2_kernel(const int* __restrict__ dst, int* __restrict__ deg2,
                            int N, long E) {
  long i = (long)blockIdx.x * blockDim.x + threadIdx.x;
  long st = (long)gridDim.x * blockDim.x;
  for (; i < E; i += st) {
    int cls = (int)((i >> 8) & (NCLS - 1));
    atomicAdd(&deg2[(size_t)cls * N + dst[i]], 1);
  }
}

// ---- exclusive scan over deg2 (M = 8N elements, order = (class, dst)) ----
__global__ __launch_bounds__(256) void scan1(const int* __restrict__ deg, int* __restrict__ starts,
                                             int* __restrict__ bsum, int M) {
  __shared__ int lds[256];
  const int tid = threadIdx.x;
  const int base = blockIdx.x * 1024 + tid * 4;
  int v0 = 0, v1 = 0, v2 = 0, v3 = 0;
  if (base + 3 < M) {
    int4 q = *(const int4*)(deg + base);
    v0 = q.x; v1 = q.y; v2 = q.z; v3 = q.w;
  } else {
    if (base + 0 < M) v0 = deg[base];
    if (base + 1 < M) v1 = deg[base + 1];
    if (base + 2 < M) v2 = deg[base + 2];
    if (base + 3 < M) v3 = deg[base + 3];
  }
  int s = v0 + v1 + v2 + v3;
  lds[tid] = s;
  __syncthreads();
  for (int off = 1; off < 256; off <<= 1) {
    int t = (tid >= off) ? lds[tid - off] : 0;
    __syncthreads();
    lds[tid] += t;
    __syncthreads();
  }
  int p = lds[tid] - s;
  if (tid == 255) bsum[blockIdx.x] = lds[255];
  if (base + 0 < M) starts[base + 0] = p; p += v0;
  if (base + 1 < M) starts[base + 1] = p; p += v1;
  if (base + 2 < M) starts[base + 2] = p; p += v2;
  if (base + 3 < M) starts[base + 3] = p;
}

// scan2: single-block parallel exclusive scan of up to 1024 block sums
__global__ __launch_bounds__(256) void scan2(int* __restrict__ bsum, int nb) {
  __shared__ int lds[256];
  const int tid = threadIdx.x;
  const int base = tid * 4;
  int v[4];
#pragma unroll
  for (int j = 0; j < 4; j++) v[j] = (base + j < nb) ? bsum[base + j] : 0;
  int s = v[0] + v[1] + v[2] + v[3];
  lds[tid] = s;
  __syncthreads();
  for (int off = 1; off < 256; off <<= 1) {
    int t = (tid >= off) ? lds[tid - off] : 0;
    __syncthreads();
    lds[tid] += t;
    __syncthreads();
  }
  int p = lds[tid] - s;
#pragma unroll
  for (int j = 0; j < 4; j++) {
    if (base + j < nb) bsum[base + j] = p;
    p += v[j];
  }
}

__global__ void scan3(int* __restrict__ starts, int* __restrict__ cursor,
                      const int* __restrict__ bsum, int M) {
  int i = blockIdx.x * 256 + threadIdx.x;
  if (i < M) {
    int v = starts[i] + bsum[i >> 10];
    starts[i] = v;
    cursor[i] = v;
  }
}

// ---- fill CSR: class-private cursor + class-private packed region ----
__global__ void fill_csr(const int* __restrict__ src, const int* __restrict__ dst,
                         const int* __restrict__ et, int* __restrict__ cursor,
                         uint* __restrict__ packed, int N, long E) {
  long i = (long)blockIdx.x * blockDim.x + threadIdx.x;
  long st = (long)gridDim.x * blockDim.x;
  for (; i < E; i += st) {
    int cls = (int)((i >> 8) & (NCLS - 1));
    int pos = atomicAdd(&cursor[(size_t)cls * N + dst[i]], 1);
    packed[pos] = ((uint)src[i] << 4) | (uint)et[i];
  }
}

// ---- wT[r][o][i] = bf16(W[r][i][o]); slot r==R is w_self ----
__global__ void build_wT(const float* __restrict__ rel, const float* __restrict__ wself,
                         ushort* __restrict__ wT, int R) {
  int id = blockIdx.x * blockDim.x + threadIdx.x;
  int total = (R + 1) * 128 * 128;
  if (id >= total) return;
  int r = id >> 14;
  int rem = id & 16383;
  int o = rem >> 7;
  int i = rem & 127;
  float v = (r < R) ? rel[((size_t)r << 14) + (i << 7) + o] : wself[(i << 7) + o];
  wT[id] = f2bf(v);
}

// ---- xw[n][r][o] = bf16( (x @ W_r)[n][o] ) ----
// 8 waves x 32 nodes = 256 nodes/block; W_r double-buffered in XOR-swizzled
// LDS; T14 split (issue loads -> MFMA -> ds_write); x-frags in registers.
__global__ __launch_bounds__(512) void xw_gemm(const float* __restrict__ x,
                                               const ushort* __restrict__ wT,
                                               ushort* __restrict__ xw,
                                               int N, int NR) {
  __shared__ ushort smem[2][16384];  // 2 x 32KB

  const int tid = threadIdx.x;
  const int lane = tid & 63;
  const int wave = tid >> 6;
  const int l15 = lane & 15;
  const int l4 = lane >> 4;
  const int nodebase = blockIdx.x * 256 + wave * 32;

  bf16x8_t xf[2][4];
  int nd[2];
#pragma unroll
  for (int g = 0; g < 2; g++) {
    int node = nodebase + g * 16 + l15;
    nd[g] = node;
    int ra = (node < N) ? node : (N - 1);
    const float* xrow = x + (size_t)ra * 128 + l4 * 8;
#pragma unroll
    for (int kk = 0; kk < 4; kk++) {
      float4 v0 = *(const float4*)(xrow + kk * 32);
      float4 v1 = *(const float4*)(xrow + kk * 32 + 4);
      bf16x8_t t;
      t[0] = (short)f2bf(v0.x); t[1] = (short)f2bf(v0.y);
      t[2] = (short)f2bf(v0.z); t[3] = (short)f2bf(v0.w);
      t[4] = (short)f2bf(v1.x); t[5] = (short)f2bf(v1.y);
      t[6] = (short)f2bf(v1.z); t[7] = (short)f2bf(v1.w);
      xf[g][kk] = t;
    }
  }

  {
    bf16x8_t sreg[4];
#pragma unroll
    for (int j = 0; j < 4; j++) {
      int c = tid + j * 512;
      sreg[j] = *(const bf16x8_t*)(wT + c * 8);
    }
#pragma unroll
    for (int j = 0; j < 4; j++) {
      int c = tid + j * 512;
      int o = c >> 4;
      int colb = (c & 15) * 16;
      int byte = o * 256 + (colb ^ ((o & 7) << 4));
      *(bf16x8_t*)((char*)smem[0] + byte) = sreg[j];
    }
  }
  __syncthreads();

  for (int r = 0; r < NR; r++) {
    bf16x8_t sreg[4];
    const bool pf = (r + 1 < NR);
    if (pf) {
      const ushort* wsrc = wT + ((size_t)(r + 1) << 14);
#pragma unroll
      for (int j = 0; j < 4; j++) {
        int c = tid + j * 512;
        sreg[j] = *(const bf16x8_t*)(wsrc + c * 8);
      }
    }

    const char* wbuf = (const char*)smem[r & 1];
#pragma unroll
    for (int nt = 0; nt < 8; nt++) {
      bf16x8_t wf[4];
      const int row = nt * 16 + l15;
      const int swz = (row & 7) << 4;
#pragma unroll
      for (int kk = 0; kk < 4; kk++) {
        int colb = l4 * 16 + kk * 64;
        wf[kk] = *(const bf16x8_t*)(wbuf + row * 256 + (colb ^ swz));
      }
#pragma unroll
      for (int g = 0; g < 2; g++) {
        f32x4_t acc = {0.f, 0.f, 0.f, 0.f};
#pragma unroll
        for (int kk = 0; kk < 4; kk++)
          acc = __builtin_amdgcn_mfma_f32_16x16x32_bf16(wf[kk], xf[g][kk], acc, 0, 0, 0);
        if (nd[g] < N) {
          ushort4 pk;
          pk.x = f2bf(acc[0]); pk.y = f2bf(acc[1]);
          pk.z = f2bf(acc[2]); pk.w = f2bf(acc[3]);
          *(ushort4*)(xw + ((size_t)nd[g] * NR + r) * 128 + nt * 16 + l4 * 4) = pk;
        }
      }
    }

    if (pf) {
#pragma unroll
      for (int j = 0; j < 4; j++) {
        int c = tid + j * 512;
        int o = c >> 4;
        int colb = (c & 15) * 16;
        int byte = o * 256 + (colb ^ ((o & 7) << 4));
        *(bf16x8_t*)((char*)smem[(r + 1) & 1] + byte) = sreg[j];
      }
    }
    __syncthreads();
  }
}

// ---- gather + fused finalize: one wave per dst node, 8 class-segments ----
__global__ __launch_bounds__(256) void gather_out(const ushort* __restrict__ xw,
                                                  const uint* __restrict__ packed,
                                                  const int* __restrict__ starts2,
                                                  const int* __restrict__ deg2,
                                                  const float* __restrict__ b,
                                                  float* __restrict__ out,
                                                  int N, int NR, int R) {
  const int lane = threadIdx.x & 63;
  const int d = blockIdx.x * 4 + (threadIdx.x >> 6);
  if (d >= N) return;
  float a0 = 0.f, a1 = 0.f;
  int dg = 0;
#pragma unroll
  for (int xc = 0; xc < NCLS; xc++) {
    const int m = xc * N + d;
    const int s0 = starts2[m];
    const int len = deg2[m];
    dg += len;
    for (int k = 0; k < len; k++) {
      uint r0 = packed[s0 + k];
      ushort2 m0 = *(const ushort2*)(xw + ((size_t)(r0 >> 4) * NR + (r0 & 15u)) * 128 + lane * 2);
      a0 += bf2f(m0.x);
      a1 += bf2f(m0.y);
    }
  }
  float inv = 1.0f / (float)((dg > 1) ? dg : 1);
  ushort2 sf = *(const ushort2*)(xw + ((size_t)d * NR + R) * 128 + lane * 2);
  float2 bb = ((const float2*)b)[lane];
  float* op = out + (size_t)d * 128 + lane * 2;
  op[0] = fmaxf(bf2f(sf.x) + bb.x + a0 * inv, 0.f);
  op[1] = fmaxf(bf2f(sf.y) + bb.y + a1 * inv, 0.f);
}

// ---- Fallback (small workspace): naive per-edge f32 GEMV ----
__global__ void deg_kernel(const int* __restrict__ dst, int* __restrict__ deg, long E) {
  long i = (long)blockIdx.x * blockDim.x + threadIdx.x;
  long st = (long)gridDim.x * blockDim.x;
  for (; i < E; i += st) atomicAdd(&deg[dst[i]], 1);
}
__global__ void naive_edge(const float* __restrict__ x, const int* __restrict__ src,
                           const int* __restrict__ dst, const int* __restrict__ et,
                           const float* __restrict__ rel, float* __restrict__ agg, long E) {
  const int lane = threadIdx.x & 63;
  long wid = ((long)blockIdx.x * blockDim.x + threadIdx.x) >> 6;
  long nw = ((long)gridDim.x * blockDim.x) >> 6;
  for (long e = wid; e < E; e += nw) {
    int s = src[e];
    int d = dst[e];
    int t = et[e];
    const float* xs = x + (size_t)s * 128;
    const float* w = rel + (size_t)t * 128 * 128;
    float a0 = 0.f, a1 = 0.f;
    for (int i = 0; i < 128; i++) {
      float xv = xs[i];
      a0 += xv * w[i * 128 + lane];
      a1 += xv * w[i * 128 + lane + 64];
    }
    atomicAdd(agg + (size_t)d * 128 + lane, a0);
    atomicAdd(agg + (size_t)d * 128 + lane + 64, a1);
  }
}
__global__ void naive_self(const float* __restrict__ x, const float* __restrict__ ws,
                           const float* __restrict__ b, const int* __restrict__ deg,
                           float* __restrict__ out, int N) {
  int v = blockIdx.x;
  int o = threadIdx.x;
  if (v >= N) return;
  const float* xv = x + (size_t)v * 128;
  float acc = b[o];
  for (int i = 0; i < 128; i++) acc += xv[i] * ws[i * 128 + o];
  float dg = (float)max(deg[v], 1);
  float val = acc + out[(size_t)v * 128 + o] / dg;
  out[(size_t)v * 128 + o] = fmaxf(val, 0.f);
}

extern "C" void kernel_launch(void* const* d_in, const int* in_sizes, int n_in,
                              void* d_out, int out_size, void* d_ws, size_t ws_size,
                              hipStream_t stream) {
  const float* x = (const float*)d_in[0];
  const int* ei = (const int*)d_in[1];
  const int* et = (const int*)d_in[2];
  const float* rel = (const float*)d_in[3];
  const float* wself = (const float*)d_in[4];
  const float* bself = (const float*)d_in[5];
  float* out = (float*)d_out;

  const int N = in_sizes[0] / 128;
  const long E = in_sizes[2];
  const int R = in_sizes[3] / (128 * 128);
  const int NR = R + 1;
  const int* srcp = ei;
  const int* dstp = ei + E;
  const int M = NCLS * N;

  // workspace layout (all 256B-aligned)
  size_t off = 0;
  auto alloc = [&](size_t bytes) {
    size_t o = off;
    off += (bytes + 255) & ~(size_t)255;
    return o;
  };
  size_t deg2_off = alloc((size_t)M * 4);
  size_t starts2_off = alloc((size_t)M * 4);
  size_t cursor2_off = alloc((size_t)M * 4);
  size_t bsum_off = alloc(4096);
  size_t wT_off = alloc((size_t)NR * 128 * 128 * 2);
  size_t packed_off = alloc((size_t)E * 4);
  size_t xw_off = alloc((size_t)N * (size_t)NR * 128 * 2);
  const bool main_path = (ws_size >= off) && (M <= 1024 * 1024);

  if (main_path) {
    int* deg2 = (int*)((char*)d_ws + deg2_off);
    int* starts2 = (int*)((char*)d_ws + starts2_off);
    int* cursor2 = (int*)((char*)d_ws + cursor2_off);
    int* bsum = (int*)((char*)d_ws + bsum_off);
    ushort* wT = (ushort*)((char*)d_ws + wT_off);
    uint* packed = (uint*)((char*)d_ws + packed_off);
    ushort* xw = (ushort*)((char*)d_ws + xw_off);

    hipMemsetAsync(deg2, 0, (size_t)M * 4, stream);
    deg2_kernel<<<2048, 256, 0, stream>>>(dstp, deg2, N, E);

    const int nb = (M + 1023) / 1024;  // <= 1024 by main_path guard
    scan1<<<nb, 256, 0, stream>>>(deg2, starts2, bsum, M);
    scan2<<<1, 256, 0, stream>>>(bsum, nb);
    scan3<<<(M + 255) / 256, 256, 0, stream>>>(starts2, cursor2, bsum, M);
    fill_csr<<<2048, 256, 0, stream>>>(srcp, dstp, et, cursor2, packed, N, E);
    build_wT<<<(NR * 16384 + 255) / 256, 256, 0, stream>>>(rel, wself, wT, R);
    xw_gemm<<<(N + 255) / 256, 512, 0, stream>>>(x, wT, xw, N, NR);
    gather_out<<<(N + 3) / 4, 256, 0, stream>>>(xw, packed, starts2, deg2, bself, out, N, NR, R);
  } else {
    int* deg = (int*)((char*)d_ws + deg2_off);
    hipMemsetAsync(deg, 0, (size_t)N * 4, stream);
    deg_kernel<<<2048, 256, 0, stream>>>(dstp, deg, E);
    hipMemsetAsync(out, 0, (size_t)out_size * 4, stream);
    naive_edge<<<4096, 256, 0, stream>>>(x, srcp, dstp, et, rel, out, E);
    naive_self<<<N, 128, 0, stream>>>(x, wself, bself, deg, out, N);
  }
}

// Round 5
// 493.911 us; speedup vs baseline: 1.1407x; 1.1407x over previous
//
#include <hip/hip_runtime.h>
#include <hip/hip_bf16.h>

typedef __attribute__((ext_vector_type(4))) float f32x4_t;
typedef __attribute__((ext_vector_type(8))) short bf16x8_t;

#define NCLS 8  // XCD count / partition classes

__device__ __forceinline__ float bf2f(ushort u) {
  return __uint_as_float(((unsigned)u) << 16);
}
__device__ __forceinline__ ushort f2bf(float f) {
  unsigned u = __float_as_uint(f);
  u += 0x7fffu + ((u >> 16) & 1u);
  return (ushort)(u >> 16);
}
__device__ __forceinline__ uint packbf2(float x, float y) {
  return (uint)f2bf(x) | ((uint)f2bf(y) << 16);
}

// ---- histogram of dst, partitioned by class(i) = (i>>8)&7 (XCD-private) ----
__global__ void deg2_kernel(const int* __restrict__ dst, int* __restrict__ deg2,
                            int N, long E) {
  long i = (long)blockIdx.x * blockDim.x + threadIdx.x;
  long st = (long)gridDim.x * blockDim.x;
  for (; i < E; i += st) {
    int cls = (int)((i >> 8) & (NCLS - 1));
    atomicAdd(&deg2[(size_t)cls * N + dst[i]], 1);
  }
}

// ---- exclusive scan over deg2 (M = 8N elements, class-major) ----
__global__ __launch_bounds__(256) void scan1(const int* __restrict__ deg, int* __restrict__ starts,
                                             int* __restrict__ bsum, int M) {
  __shared__ int lds[256];
  const int tid = threadIdx.x;
  const int base = blockIdx.x * 1024 + tid * 4;
  int v0 = 0, v1 = 0, v2 = 0, v3 = 0;
  if (base + 3 < M) {
    int4 q = *(const int4*)(deg + base);
    v0 = q.x; v1 = q.y; v2 = q.z; v3 = q.w;
  } else {
    if (base + 0 < M) v0 = deg[base];
    if (base + 1 < M) v1 = deg[base + 1];
    if (base + 2 < M) v2 = deg[base + 2];
    if (base + 3 < M) v3 = deg[base + 3];
  }
  int s = v0 + v1 + v2 + v3;
  lds[tid] = s;
  __syncthreads();
  for (int off = 1; off < 256; off <<= 1) {
    int t = (tid >= off) ? lds[tid - off] : 0;
    __syncthreads();
    lds[tid] += t;
    __syncthreads();
  }
  int p = lds[tid] - s;
  if (tid == 255) bsum[blockIdx.x] = lds[255];
  if (base + 0 < M) starts[base + 0] = p; p += v0;
  if (base + 1 < M) starts[base + 1] = p; p += v1;
  if (base + 2 < M) starts[base + 2] = p; p += v2;
  if (base + 3 < M) starts[base + 3] = p;
}

__global__ __launch_bounds__(256) void scan2(int* __restrict__ bsum, int nb) {
  __shared__ int lds[256];
  const int tid = threadIdx.x;
  const int base = tid * 4;
  int v[4];
#pragma unroll
  for (int j = 0; j < 4; j++) v[j] = (base + j < nb) ? bsum[base + j] : 0;
  int s = v[0] + v[1] + v[2] + v[3];
  lds[tid] = s;
  __syncthreads();
  for (int off = 1; off < 256; off <<= 1) {
    int t = (tid >= off) ? lds[tid - off] : 0;
    __syncthreads();
    lds[tid] += t;
    __syncthreads();
  }
  int p = lds[tid] - s;
#pragma unroll
  for (int j = 0; j < 4; j++) {
    if (base + j < nb) bsum[base + j] = p;
    p += v[j];
  }
}

__global__ void scan3(int* __restrict__ starts, int* __restrict__ cursor,
                      const int* __restrict__ bsum, int M) {
  int i = blockIdx.x * 256 + threadIdx.x;
  if (i < M) {
    int v = starts[i] + bsum[i >> 10];
    starts[i] = v;
    cursor[i] = v;
  }
}

// ---- fill CSR: class-private cursor + class-private packed region ----
__global__ void fill_csr(const int* __restrict__ src, const int* __restrict__ dst,
                         const int* __restrict__ et, int* __restrict__ cursor,
                         uint* __restrict__ packed, int N, long E) {
  long i = (long)blockIdx.x * blockDim.x + threadIdx.x;
  long st = (long)gridDim.x * blockDim.x;
  for (; i < E; i += st) {
    int cls = (int)((i >> 8) & (NCLS - 1));
    int pos = atomicAdd(&cursor[(size_t)cls * N + dst[i]], 1);
    packed[pos] = ((uint)src[i] << 4) | (uint)et[i];
  }
}

// ---- wT[r][o][i] = bf16(W[r][i][o]); slot r==R is w_self ----
__global__ void build_wT(const float* __restrict__ rel, const float* __restrict__ wself,
                         ushort* __restrict__ wT, int R) {
  int id = blockIdx.x * blockDim.x + threadIdx.x;
  int total = (R + 1) * 128 * 128;
  if (id >= total) return;
  int r = id >> 14;
  int rem = id & 16383;
  int o = rem >> 7;
  int i = rem & 127;
  float v = (r < R) ? rel[((size_t)r << 14) + (i << 7) + o] : wself[(i << 7) + o];
  wT[id] = f2bf(v);
}

// ---- x (f32) -> bf16, stored as row NR-1(=8) of each node's S slab ----
__global__ void conv_x_kernel(const float* __restrict__ x, ushort* __restrict__ S,
                              long n4, int NR) {
  long i = (long)blockIdx.x * blockDim.x + threadIdx.x;
  long st = (long)gridDim.x * blockDim.x;
  const int rowstride = NR * 128;
  const int selfoff = (NR - 1) * 128;
  for (; i < n4; i += st) {
    long node = i >> 5;
    int w = (int)(i & 31) * 4;
    float4 v = ((const float4*)x)[i];
    ushort4 o;
    o.x = f2bf(v.x); o.y = f2bf(v.y); o.z = f2bf(v.z); o.w = f2bf(v.w);
    *(ushort4*)(S + (size_t)node * rowstride + selfoff + w) = o;
  }
}

// ---- gather_sum: one wave per dst node. Sums bf16 x-rows (read from S's
// self rows, 26MB working set: L2/L3-resident) into 8 per-type f32 accs,
// pre-scales by 1/deg, writes S rows 0..7 (nontemporal, bf16). ----
__global__ __launch_bounds__(256) void gather_sum(const uint* __restrict__ packed,
                                                  const int* __restrict__ starts2,
                                                  const int* __restrict__ deg2,
                                                  ushort* __restrict__ S,
                                                  int N, int NR) {
  const int lane = threadIdx.x & 63;
  const int d = blockIdx.x * 4 + (threadIdx.x >> 6);
  if (d >= N) return;
  const int rowstride = NR * 128;
  const size_t selfoff = (size_t)(NR - 1) * 128;

  // prefetch all segment headers (independent loads, no serial chain)
  int s0[NCLS], ln[NCLS];
#pragma unroll
  for (int c = 0; c < NCLS; c++) s0[c] = starts2[c * N + d];
#pragma unroll
  for (int c = 0; c < NCLS; c++) ln[c] = deg2[c * N + d];

  float a0x = 0, a0y = 0, a1x = 0, a1y = 0, a2x = 0, a2y = 0, a3x = 0, a3y = 0;
  float a4x = 0, a4y = 0, a5x = 0, a5y = 0, a6x = 0, a6y = 0, a7x = 0, a7y = 0;

#define ACCUM(t, vx, vy)                                  \
  switch (t) {                                            \
    case 0: a0x += vx; a0y += vy; break;                  \
    case 1: a1x += vx; a1y += vy; break;                  \
    case 2: a2x += vx; a2y += vy; break;                  \
    case 3: a3x += vx; a3y += vy; break;                  \
    case 4: a4x += vx; a4y += vy; break;                  \
    case 5: a5x += vx; a5y += vy; break;                  \
    case 6: a6x += vx; a6y += vy; break;                  \
    default: a7x += vx; a7y += vy; break;                 \
  }

  int dg = 0;
#pragma unroll 1
  for (int c = 0; c < NCLS; c++) {
    int e = s0[c];
    const int e1 = e + ln[c];
    dg += ln[c];
    for (; e + 1 < e1; e += 2) {
      uint r0 = packed[e], r1 = packed[e + 1];
      ushort2 m0 = *(const ushort2*)(S + (size_t)(r0 >> 4) * rowstride + selfoff + lane * 2);
      ushort2 m1 = *(const ushort2*)(S + (size_t)(r1 >> 4) * rowstride + selfoff + lane * 2);
      float x0 = bf2f(m0.x), y0 = bf2f(m0.y);
      float x1 = bf2f(m1.x), y1 = bf2f(m1.y);
      int t0 = (int)(r0 & 15u), t1 = (int)(r1 & 15u);
      ACCUM(t0, x0, y0);
      ACCUM(t1, x1, y1);
    }
    if (e < e1) {
      uint r0 = packed[e];
      ushort2 m0 = *(const ushort2*)(S + (size_t)(r0 >> 4) * rowstride + selfoff + lane * 2);
      float x0 = bf2f(m0.x), y0 = bf2f(m0.y);
      int t0 = (int)(r0 & 15u);
      ACCUM(t0, x0, y0);
    }
  }
#undef ACCUM

  const float inv = 1.0f / (float)((dg > 1) ? dg : 1);
  uint* Sd = (uint*)(S + (size_t)d * rowstride) + lane;  // ushort2 slot per lane
  __builtin_nontemporal_store(packbf2(a0x * inv, a0y * inv), Sd + 0 * 64);
  __builtin_nontemporal_store(packbf2(a1x * inv, a1y * inv), Sd + 1 * 64);
  __builtin_nontemporal_store(packbf2(a2x * inv, a2y * inv), Sd + 2 * 64);
  __builtin_nontemporal_store(packbf2(a3x * inv, a3y * inv), Sd + 3 * 64);
  __builtin_nontemporal_store(packbf2(a4x * inv, a4y * inv), Sd + 4 * 64);
  __builtin_nontemporal_store(packbf2(a5x * inv, a5y * inv), Sd + 5 * 64);
  __builtin_nontemporal_store(packbf2(a6x * inv, a6y * inv), Sd + 6 * 64);
  __builtin_nontemporal_store(packbf2(a7x * inv, a7y * inv), Sd + 7 * 64);
}

// ---- agg_gemm: out[d] = relu( sum_r S[d][r] @ W_r + b ).
// 8 waves x 32 nodes = 256 nodes/block; W_r double-buffered in XOR-swizzled
// LDS (reg-staged, proven R3 structure); acc held across all 9 relations. ----
__global__ __launch_bounds__(512) void agg_gemm(const ushort* __restrict__ S,
                                                const ushort* __restrict__ wT,
                                                const float* __restrict__ b,
                                                float* __restrict__ out,
                                                int N, int NR) {
  __shared__ ushort smem[2][16384];  // 2 x 32KB

  const int tid = threadIdx.x;
  const int lane = tid & 63;
  const int wave = tid >> 6;
  const int l15 = lane & 15;
  const int l4 = lane >> 4;
  const int nodebase = blockIdx.x * 256 + wave * 32;

  int nd[2], rd[2];
  nd[0] = nodebase + l15;
  nd[1] = nodebase + 16 + l15;
  rd[0] = (nd[0] < N) ? nd[0] : (N - 1);
  rd[1] = (nd[1] < N) ? nd[1] : (N - 1);

  f32x4_t acc[2][8];
#pragma unroll
  for (int g = 0; g < 2; g++)
#pragma unroll
    for (int nt = 0; nt < 8; nt++) acc[g][nt] = {0.f, 0.f, 0.f, 0.f};

  // prologue: stage W_0 into buf 0
  {
    bf16x8_t sreg[4];
#pragma unroll
    for (int j = 0; j < 4; j++) {
      int c = tid + j * 512;
      sreg[j] = *(const bf16x8_t*)(wT + c * 8);
    }
#pragma unroll
    for (int j = 0; j < 4; j++) {
      int c = tid + j * 512;
      int o = c >> 4;
      int colb = (c & 15) * 16;
      int byte = o * 256 + (colb ^ ((o & 7) << 4));
      *(bf16x8_t*)((char*)smem[0] + byte) = sreg[j];
    }
  }
  __syncthreads();

  for (int r = 0; r < NR; r++) {
    // S-fragments for this relation (row r of each node's slab)
    bf16x8_t sf[2][4];
#pragma unroll
    for (int g = 0; g < 2; g++) {
      const ushort* srow = S + ((size_t)rd[g] * NR + r) * 128 + l4 * 8;
#pragma unroll
      for (int kk = 0; kk < 4; kk++)
        sf[g][kk] = *(const bf16x8_t*)(srow + kk * 32);
    }

    // prefetch next W (T14: issue before MFMA cluster)
    bf16x8_t sreg[4];
    const bool pf = (r + 1 < NR);
    if (pf) {
      const ushort* wsrc = wT + ((size_t)(r + 1) << 14);
#pragma unroll
      for (int j = 0; j < 4; j++) {
        int c = tid + j * 512;
        sreg[j] = *(const bf16x8_t*)(wsrc + c * 8);
      }
    }

    const char* wbuf = (const char*)smem[r & 1];
#pragma unroll
    for (int nt = 0; nt < 8; nt++) {
      bf16x8_t wf[4];
      const int row = nt * 16 + l15;
      const int swz = (row & 7) << 4;
#pragma unroll
      for (int kk = 0; kk < 4; kk++) {
        int colb = l4 * 16 + kk * 64;
        wf[kk] = *(const bf16x8_t*)(wbuf + row * 256 + (colb ^ swz));
      }
#pragma unroll
      for (int g = 0; g < 2; g++)
#pragma unroll
        for (int kk = 0; kk < 4; kk++)
          acc[g][nt] = __builtin_amdgcn_mfma_f32_16x16x32_bf16(wf[kk], sf[g][kk], acc[g][nt], 0, 0, 0);
    }

    if (pf) {
#pragma unroll
      for (int j = 0; j < 4; j++) {
        int c = tid + j * 512;
        int o = c >> 4;
        int colb = (c & 15) * 16;
        int byte = o * 256 + (colb ^ ((o & 7) << 4));
        *(bf16x8_t*)((char*)smem[(r + 1) & 1] + byte) = sreg[j];
      }
    }
    __syncthreads();
  }

  // epilogue: out = relu(acc + b)
#pragma unroll
  for (int g = 0; g < 2; g++) {
    if (nd[g] < N) {
#pragma unroll
      for (int nt = 0; nt < 8; nt++) {
        float4 bv = *(const float4*)(b + nt * 16 + l4 * 4);
        f32x4_t v = acc[g][nt];
        float4 o;
        o.x = fmaxf(v[0] + bv.x, 0.f);
        o.y = fmaxf(v[1] + bv.y, 0.f);
        o.z = fmaxf(v[2] + bv.z, 0.f);
        o.w = fmaxf(v[3] + bv.w, 0.f);
        *(float4*)(out + (size_t)nd[g] * 128 + nt * 16 + l4 * 4) = o;
      }
    }
  }
}

// ---- Fallback (small workspace): naive per-edge f32 GEMV ----
__global__ void deg_kernel(const int* __restrict__ dst, int* __restrict__ deg, long E) {
  long i = (long)blockIdx.x * blockDim.x + threadIdx.x;
  long st = (long)gridDim.x * blockDim.x;
  for (; i < E; i += st) atomicAdd(&deg[dst[i]], 1);
}
__global__ void naive_edge(const float* __restrict__ x, const int* __restrict__ src,
                           const int* __restrict__ dst, const int* __restrict__ et,
                           const float* __restrict__ rel, float* __restrict__ agg, long E) {
  const int lane = threadIdx.x & 63;
  long wid = ((long)blockIdx.x * blockDim.x + threadIdx.x) >> 6;
  long nw = ((long)gridDim.x * blockDim.x) >> 6;
  for (long e = wid; e < E; e += nw) {
    int s = src[e];
    int d = dst[e];
    int t = et[e];
    const float* xs = x + (size_t)s * 128;
    const float* w = rel + (size_t)t * 128 * 128;
    float a0 = 0.f, a1 = 0.f;
    for (int i = 0; i < 128; i++) {
      float xv = xs[i];
      a0 += xv * w[i * 128 + lane];
      a1 += xv * w[i * 128 + lane + 64];
    }
    atomicAdd(agg + (size_t)d * 128 + lane, a0);
    atomicAdd(agg + (size_t)d * 128 + lane + 64, a1);
  }
}
__global__ void naive_self(const float* __restrict__ x, const float* __restrict__ ws,
                           const float* __restrict__ b, const int* __restrict__ deg,
                           float* __restrict__ out, int N) {
  int v = blockIdx.x;
  int o = threadIdx.x;
  if (v >= N) return;
  const float* xv = x + (size_t)v * 128;
  float acc = b[o];
  for (int i = 0; i < 128; i++) acc += xv[i] * ws[i * 128 + o];
  float dg = (float)max(deg[v], 1);
  float val = acc + out[(size_t)v * 128 + o] / dg;
  out[(size_t)v * 128 + o] = fmaxf(val, 0.f);
}

extern "C" void kernel_launch(void* const* d_in, const int* in_sizes, int n_in,
                              void* d_out, int out_size, void* d_ws, size_t ws_size,
                              hipStream_t stream) {
  const float* x = (const float*)d_in[0];
  const int* ei = (const int*)d_in[1];
  const int* et = (const int*)d_in[2];
  const float* rel = (const float*)d_in[3];
  const float* wself = (const float*)d_in[4];
  const float* bself = (const float*)d_in[5];
  float* out = (float*)d_out;

  const int N = in_sizes[0] / 128;
  const long E = in_sizes[2];
  const int R = in_sizes[3] / (128 * 128);
  const int NR = R + 1;
  const int* srcp = ei;
  const int* dstp = ei + E;
  const int M = NCLS * N;

  // workspace layout (all 256B-aligned)
  size_t off = 0;
  auto alloc = [&](size_t bytes) {
    size_t o = off;
    off += (bytes + 255) & ~(size_t)255;
    return o;
  };
  size_t deg2_off = alloc((size_t)M * 4);
  size_t starts2_off = alloc((size_t)M * 4);
  size_t cursor2_off = alloc((size_t)M * 4);
  size_t bsum_off = alloc(4096);
  size_t wT_off = alloc((size_t)NR * 128 * 128 * 2);
  size_t packed_off = alloc((size_t)E * 4);
  size_t S_off = alloc((size_t)N * (size_t)NR * 128 * 2);
  const bool main_path = (ws_size >= off) && (M <= 1024 * 1024) && (R <= 8);

  if (main_path) {
    int* deg2 = (int*)((char*)d_ws + deg2_off);
    int* starts2 = (int*)((char*)d_ws + starts2_off);
    int* cursor2 = (int*)((char*)d_ws + cursor2_off);
    int* bsum = (int*)((char*)d_ws + bsum_off);
    ushort* wT = (ushort*)((char*)d_ws + wT_off);
    uint* packed = (uint*)((char*)d_ws + packed_off);
    ushort* S = (ushort*)((char*)d_ws + S_off);

    hipMemsetAsync(deg2, 0, (size_t)M * 4, stream);
    deg2_kernel<<<2048, 256, 0, stream>>>(dstp, deg2, N, E);

    const int nb = (M + 1023) / 1024;
    scan1<<<nb, 256, 0, stream>>>(deg2, starts2, bsum, M);
    scan2<<<1, 256, 0, stream>>>(bsum, nb);
    scan3<<<(M + 255) / 256, 256, 0, stream>>>(starts2, cursor2, bsum, M);
    fill_csr<<<2048, 256, 0, stream>>>(srcp, dstp, et, cursor2, packed, N, E);
    conv_x_kernel<<<2048, 256, 0, stream>>>(x, S, (long)N * 32, NR);
    build_wT<<<(NR * 16384 + 255) / 256, 256, 0, stream>>>(rel, wself, wT, R);
    gather_sum<<<(N + 3) / 4, 256, 0, stream>>>(packed, starts2, deg2, S, N, NR);
    agg_gemm<<<(N + 255) / 256, 512, 0, stream>>>(S, wT, bself, out, N, NR);
  } else {
    int* deg = (int*)((char*)d_ws + deg2_off);
    hipMemsetAsync(deg, 0, (size_t)N * 4, stream);
    deg_kernel<<<2048, 256, 0, stream>>>(dstp, deg, E);
    hipMemsetAsync(out, 0, (size_t)out_size * 4, stream);
    naive_edge<<<4096, 256, 0, stream>>>(x, srcp, dstp, et, rel, out, E);
    naive_self<<<N, 128, 0, stream>>>(x, wself, bself, deg, out, N);
  }
}

// Round 6
// 463.669 us; speedup vs baseline: 1.2151x; 1.0652x over previous
//
#include <hip/hip_runtime.h>
#include <hip/hip_bf16.h>

typedef __attribute__((ext_vector_type(4))) float f32x4_t;
typedef __attribute__((ext_vector_type(8))) short bf16x8_t;

#define NCLS 8  // XCD count / partition classes

__device__ __forceinline__ float bf2f(ushort u) {
  return __uint_as_float(((unsigned)u) << 16);
}
__device__ __forceinline__ ushort f2bf(float f) {
  unsigned u = __float_as_uint(f);
  u += 0x7fffu + ((u >> 16) & 1u);
  return (ushort)(u >> 16);
}
__device__ __forceinline__ uint packbf2(float x, float y) {
  return (uint)f2bf(x) | ((uint)f2bf(y) << 16);
}

// ---- histogram of dst, partitioned by class(i) = (i>>8)&7 (XCD-private) ----
__global__ void deg2_kernel(const int* __restrict__ dst, int* __restrict__ deg2,
                            int N, long E) {
  long i = (long)blockIdx.x * blockDim.x + threadIdx.x;
  long st = (long)gridDim.x * blockDim.x;
  for (; i < E; i += st) {
    int cls = (int)((i >> 8) & (NCLS - 1));
    atomicAdd(&deg2[(size_t)cls * N + dst[i]], 1);
  }
}

// ---- nodedeg[d] = sum_c deg2[c][d] (coalesced per class iteration) ----
__global__ void nodedeg_kernel(const int* __restrict__ deg2, int* __restrict__ nodedeg, int N) {
  int d = blockIdx.x * 256 + threadIdx.x;
  if (d >= N) return;
  int s = 0;
#pragma unroll
  for (int c = 0; c < NCLS; c++) s += deg2[(size_t)c * N + d];
  nodedeg[d] = s;
}

// ---- exclusive scan over nodedeg (N elements) ----
__global__ __launch_bounds__(256) void scan1(const int* __restrict__ deg, int* __restrict__ starts,
                                             int* __restrict__ bsum, int M) {
  __shared__ int lds[256];
  const int tid = threadIdx.x;
  const int base = blockIdx.x * 1024 + tid * 4;
  int v0 = 0, v1 = 0, v2 = 0, v3 = 0;
  if (base + 3 < M) {
    int4 q = *(const int4*)(deg + base);
    v0 = q.x; v1 = q.y; v2 = q.z; v3 = q.w;
  } else {
    if (base + 0 < M) v0 = deg[base];
    if (base + 1 < M) v1 = deg[base + 1];
    if (base + 2 < M) v2 = deg[base + 2];
    if (base + 3 < M) v3 = deg[base + 3];
  }
  int s = v0 + v1 + v2 + v3;
  lds[tid] = s;
  __syncthreads();
  for (int off = 1; off < 256; off <<= 1) {
    int t = (tid >= off) ? lds[tid - off] : 0;
    __syncthreads();
    lds[tid] += t;
    __syncthreads();
  }
  int p = lds[tid] - s;
  if (tid == 255) bsum[blockIdx.x] = lds[255];
  if (base + 0 < M) starts[base + 0] = p; p += v0;
  if (base + 1 < M) starts[base + 1] = p; p += v1;
  if (base + 2 < M) starts[base + 2] = p; p += v2;
  if (base + 3 < M) starts[base + 3] = p;
}

__global__ __launch_bounds__(256) void scan2(int* __restrict__ bsum, int nb) {
  __shared__ int lds[256];
  const int tid = threadIdx.x;
  const int base = tid * 4;
  int v[4];
#pragma unroll
  for (int j = 0; j < 4; j++) v[j] = (base + j < nb) ? bsum[base + j] : 0;
  int s = v[0] + v[1] + v[2] + v[3];
  lds[tid] = s;
  __syncthreads();
  for (int off = 1; off < 256; off <<= 1) {
    int t = (tid >= off) ? lds[tid - off] : 0;
    __syncthreads();
    lds[tid] += t;
    __syncthreads();
  }
  int p = lds[tid] - s;
#pragma unroll
  for (int j = 0; j < 4; j++) {
    if (base + j < nb) bsum[base + j] = p;
    p += v[j];
  }
}

__global__ void scan3(int* __restrict__ starts, const int* __restrict__ bsum, int M) {
  int i = blockIdx.x * 256 + threadIdx.x;
  if (i < M) starts[i] += bsum[i >> 10];
}

// ---- cursor[c][d] = node_start[d] + sum_{c'<c} deg2[c'][d] ----
// Positions are dst-major (one contiguous run per node) while the cursor
// ARRAY stays class-major so fill's atomic lines remain XCD-private.
__global__ void cursor_init(const int* __restrict__ deg2, const int* __restrict__ node_starts,
                            int* __restrict__ cursor, int N) {
  int d = blockIdx.x * 256 + threadIdx.x;
  if (d >= N) return;
  int run = node_starts[d];
#pragma unroll
  for (int c = 0; c < NCLS; c++) {
    cursor[(size_t)c * N + d] = run;
    run += deg2[(size_t)c * N + d];
  }
}

// ---- fill CSR: class-private cursor, dst-contiguous packed ----
__global__ void fill_csr(const int* __restrict__ src, const int* __restrict__ dst,
                         const int* __restrict__ et, int* __restrict__ cursor,
                         uint* __restrict__ packed, int N, long E) {
  long i = (long)blockIdx.x * blockDim.x + threadIdx.x;
  long st = (long)gridDim.x * blockDim.x;
  for (; i < E; i += st) {
    int cls = (int)((i >> 8) & (NCLS - 1));
    int pos = atomicAdd(&cursor[(size_t)cls * N + dst[i]], 1);
    packed[pos] = ((uint)src[i] << 4) | (uint)et[i];
  }
}

// ---- wT[r][o][i] = bf16(W[r][i][o]); slot r==R is w_self ----
__global__ void build_wT(const float* __restrict__ rel, const float* __restrict__ wself,
                         ushort* __restrict__ wT, int R) {
  int id = blockIdx.x * blockDim.x + threadIdx.x;
  int total = (R + 1) * 128 * 128;
  if (id >= total) return;
  int r = id >> 14;
  int rem = id & 16383;
  int o = rem >> 7;
  int i = rem & 127;
  float v = (r < R) ? rel[((size_t)r << 14) + (i << 7) + o] : wself[(i << 7) + o];
  wT[id] = f2bf(v);
}

// ---- x (f32) -> compact bf16 xb (26MB, L3-resident) ----
__global__ void conv_x_kernel(const float* __restrict__ x, ushort* __restrict__ xb, long n4) {
  long i = (long)blockIdx.x * blockDim.x + threadIdx.x;
  long st = (long)gridDim.x * blockDim.x;
  for (; i < n4; i += st) {
    float4 v = ((const float4*)x)[i];
    ushort4 o;
    o.x = f2bf(v.x); o.y = f2bf(v.y); o.z = f2bf(v.z); o.w = f2bf(v.w);
    ((ushort4*)xb)[i] = o;
  }
}

// ---- gather_sum: one wave per dst node; ONE contiguous edge run; 4-unroll.
// Sums bf16 xb rows into 8 per-type f32 accs, pre-scales by 1/deg,
// writes S rows 0..7 (bf16, nontemporal). ----
__global__ __launch_bounds__(256) void gather_sum(const uint* __restrict__ packed,
                                                  const int* __restrict__ node_starts,
                                                  const int* __restrict__ nodedeg,
                                                  const ushort* __restrict__ xb,
                                                  ushort* __restrict__ S,
                                                  int N) {
  const int lane = threadIdx.x & 63;
  const int d = blockIdx.x * 4 + (threadIdx.x >> 6);
  if (d >= N) return;

  const int s0 = node_starts[d];
  const int dg = nodedeg[d];
  const int e1 = s0 + dg;

  float a0x = 0, a0y = 0, a1x = 0, a1y = 0, a2x = 0, a2y = 0, a3x = 0, a3y = 0;
  float a4x = 0, a4y = 0, a5x = 0, a5y = 0, a6x = 0, a6y = 0, a7x = 0, a7y = 0;

#define ACCUM(t, vx, vy)                                  \
  switch (t) {                                            \
    case 0: a0x += vx; a0y += vy; break;                  \
    case 1: a1x += vx; a1y += vy; break;                  \
    case 2: a2x += vx; a2y += vy; break;                  \
    case 3: a3x += vx; a3y += vy; break;                  \
    case 4: a4x += vx; a4y += vy; break;                  \
    case 5: a5x += vx; a5y += vy; break;                  \
    case 6: a6x += vx; a6y += vy; break;                  \
    default: a7x += vx; a7y += vy; break;                 \
  }

  int e = s0;
  for (; e + 3 < e1; e += 4) {
    uint r0 = packed[e], r1 = packed[e + 1], r2 = packed[e + 2], r3 = packed[e + 3];
    ushort2 m0 = *(const ushort2*)(xb + (size_t)(r0 >> 4) * 128 + lane * 2);
    ushort2 m1 = *(const ushort2*)(xb + (size_t)(r1 >> 4) * 128 + lane * 2);
    ushort2 m2 = *(const ushort2*)(xb + (size_t)(r2 >> 4) * 128 + lane * 2);
    ushort2 m3 = *(const ushort2*)(xb + (size_t)(r3 >> 4) * 128 + lane * 2);
    int t0 = (int)(r0 & 15u), t1 = (int)(r1 & 15u);
    int t2 = (int)(r2 & 15u), t3 = (int)(r3 & 15u);
    ACCUM(t0, bf2f(m0.x), bf2f(m0.y));
    ACCUM(t1, bf2f(m1.x), bf2f(m1.y));
    ACCUM(t2, bf2f(m2.x), bf2f(m2.y));
    ACCUM(t3, bf2f(m3.x), bf2f(m3.y));
  }
  for (; e < e1; e++) {
    uint r0 = packed[e];
    ushort2 m0 = *(const ushort2*)(xb + (size_t)(r0 >> 4) * 128 + lane * 2);
    int t0 = (int)(r0 & 15u);
    ACCUM(t0, bf2f(m0.x), bf2f(m0.y));
  }
#undef ACCUM

  const float inv = 1.0f / (float)((dg > 1) ? dg : 1);
  uint* Sd = (uint*)(S + (size_t)d * 1024) + lane;  // 8 rows x 128 bf16 per node
  __builtin_nontemporal_store(packbf2(a0x * inv, a0y * inv), Sd + 0 * 64);
  __builtin_nontemporal_store(packbf2(a1x * inv, a1y * inv), Sd + 1 * 64);
  __builtin_nontemporal_store(packbf2(a2x * inv, a2y * inv), Sd + 2 * 64);
  __builtin_nontemporal_store(packbf2(a3x * inv, a3y * inv), Sd + 3 * 64);
  __builtin_nontemporal_store(packbf2(a4x * inv, a4y * inv), Sd + 4 * 64);
  __builtin_nontemporal_store(packbf2(a5x * inv, a5y * inv), Sd + 5 * 64);
  __builtin_nontemporal_store(packbf2(a6x * inv, a6y * inv), Sd + 6 * 64);
  __builtin_nontemporal_store(packbf2(a7x * inv, a7y * inv), Sd + 7 * 64);
}

// ---- agg_gemm: out[d] = relu( sum_{r<8} S[d][r] @ W_r + xb[d] @ W_self + b ).
// 8 waves x 32 nodes = 256 nodes/block; W_r double-buffered in XOR-swizzled
// LDS; acc held across all 9 relations; self fragment read from compact xb. ----
__global__ __launch_bounds__(512) void agg_gemm(const ushort* __restrict__ S,
                                                const ushort* __restrict__ xb,
                                                const ushort* __restrict__ wT,
                                                const float* __restrict__ b,
                                                float* __restrict__ out,
                                                int N, int NR) {
  __shared__ ushort smem[2][16384];  // 2 x 32KB

  const int tid = threadIdx.x;
  const int lane = tid & 63;
  const int wave = tid >> 6;
  const int l15 = lane & 15;
  const int l4 = lane >> 4;
  const int nodebase = blockIdx.x * 256 + wave * 32;

  int nd[2], rd[2];
  nd[0] = nodebase + l15;
  nd[1] = nodebase + 16 + l15;
  rd[0] = (nd[0] < N) ? nd[0] : (N - 1);
  rd[1] = (nd[1] < N) ? nd[1] : (N - 1);

  f32x4_t acc[2][8];
#pragma unroll
  for (int g = 0; g < 2; g++)
#pragma unroll
    for (int nt = 0; nt < 8; nt++) acc[g][nt] = {0.f, 0.f, 0.f, 0.f};

  // prologue: stage W_0 into buf 0
  {
    bf16x8_t sreg[4];
#pragma unroll
    for (int j = 0; j < 4; j++) {
      int c = tid + j * 512;
      sreg[j] = *(const bf16x8_t*)(wT + c * 8);
    }
#pragma unroll
    for (int j = 0; j < 4; j++) {
      int c = tid + j * 512;
      int o = c >> 4;
      int colb = (c & 15) * 16;
      int byte = o * 256 + (colb ^ ((o & 7) << 4));
      *(bf16x8_t*)((char*)smem[0] + byte) = sreg[j];
    }
  }
  __syncthreads();

  for (int r = 0; r < NR; r++) {
    // S-fragments for this relation (self term comes from compact xb)
    bf16x8_t sf[2][4];
#pragma unroll
    for (int g = 0; g < 2; g++) {
      const ushort* srow = (r < NR - 1) ? (S + ((size_t)rd[g] * 8 + r) * 128 + l4 * 8)
                                        : (xb + (size_t)rd[g] * 128 + l4 * 8);
#pragma unroll
      for (int kk = 0; kk < 4; kk++)
        sf[g][kk] = *(const bf16x8_t*)(srow + kk * 32);
    }

    // prefetch next W (T14: issue before MFMA cluster)
    bf16x8_t sreg[4];
    const bool pf = (r + 1 < NR);
    if (pf) {
      const ushort* wsrc = wT + ((size_t)(r + 1) << 14);
#pragma unroll
      for (int j = 0; j < 4; j++) {
        int c = tid + j * 512;
        sreg[j] = *(const bf16x8_t*)(wsrc + c * 8);
      }
    }

    const char* wbuf = (const char*)smem[r & 1];
#pragma unroll
    for (int nt = 0; nt < 8; nt++) {
      bf16x8_t wf[4];
      const int row = nt * 16 + l15;
      const int swz = (row & 7) << 4;
#pragma unroll
      for (int kk = 0; kk < 4; kk++) {
        int colb = l4 * 16 + kk * 64;
        wf[kk] = *(const bf16x8_t*)(wbuf + row * 256 + (colb ^ swz));
      }
#pragma unroll
      for (int g = 0; g < 2; g++)
#pragma unroll
        for (int kk = 0; kk < 4; kk++)
          acc[g][nt] = __builtin_amdgcn_mfma_f32_16x16x32_bf16(wf[kk], sf[g][kk], acc[g][nt], 0, 0, 0);
    }

    if (pf) {
#pragma unroll
      for (int j = 0; j < 4; j++) {
        int c = tid + j * 512;
        int o = c >> 4;
        int colb = (c & 15) * 16;
        int byte = o * 256 + (colb ^ ((o & 7) << 4));
        *(bf16x8_t*)((char*)smem[(r + 1) & 1] + byte) = sreg[j];
      }
    }
    __syncthreads();
  }

  // epilogue: out = relu(acc + b)
#pragma unroll
  for (int g = 0; g < 2; g++) {
    if (nd[g] < N) {
#pragma unroll
      for (int nt = 0; nt < 8; nt++) {
        float4 bv = *(const float4*)(b + nt * 16 + l4 * 4);
        f32x4_t v = acc[g][nt];
        float4 o;
        o.x = fmaxf(v[0] + bv.x, 0.f);
        o.y = fmaxf(v[1] + bv.y, 0.f);
        o.z = fmaxf(v[2] + bv.z, 0.f);
        o.w = fmaxf(v[3] + bv.w, 0.f);
        *(float4*)(out + (size_t)nd[g] * 128 + nt * 16 + l4 * 4) = o;
      }
    }
  }
}

// ---- Fallback (small workspace): naive per-edge f32 GEMV ----
__global__ void deg_kernel(const int* __restrict__ dst, int* __restrict__ deg, long E) {
  long i = (long)blockIdx.x * blockDim.x + threadIdx.x;
  long st = (long)gridDim.x * blockDim.x;
  for (; i < E; i += st) atomicAdd(&deg[dst[i]], 1);
}
__global__ void naive_edge(const float* __restrict__ x, const int* __restrict__ src,
                           const int* __restrict__ dst, const int* __restrict__ et,
                           const float* __restrict__ rel, float* __restrict__ agg, long E) {
  const int lane = threadIdx.x & 63;
  long wid = ((long)blockIdx.x * blockDim.x + threadIdx.x) >> 6;
  long nw = ((long)gridDim.x * blockDim.x) >> 6;
  for (long e = wid; e < E; e += nw) {
    int s = src[e];
    int d = dst[e];
    int t = et[e];
    const float* xs = x + (size_t)s * 128;
    const float* w = rel + (size_t)t * 128 * 128;
    float a0 = 0.f, a1 = 0.f;
    for (int i = 0; i < 128; i++) {
      float xv = xs[i];
      a0 += xv * w[i * 128 + lane];
      a1 += xv * w[i * 128 + lane + 64];
    }
    atomicAdd(agg + (size_t)d * 128 + lane, a0);
    atomicAdd(agg + (size_t)d * 128 + lane + 64, a1);
  }
}
__global__ void naive_self(const float* __restrict__ x, const float* __restrict__ ws,
                           const float* __restrict__ b, const int* __restrict__ deg,
                           float* __restrict__ out, int N) {
  int v = blockIdx.x;
  int o = threadIdx.x;
  if (v >= N) return;
  const float* xv = x + (size_t)v * 128;
  float acc = b[o];
  for (int i = 0; i < 128; i++) acc += xv[i] * ws[i * 128 + o];
  float dg = (float)max(deg[v], 1);
  float val = acc + out[(size_t)v * 128 + o] / dg;
  out[(size_t)v * 128 + o] = fmaxf(val, 0.f);
}

extern "C" void kernel_launch(void* const* d_in, const int* in_sizes, int n_in,
                              void* d_out, int out_size, void* d_ws, size_t ws_size,
                              hipStream_t stream) {
  const float* x = (const float*)d_in[0];
  const int* ei = (const int*)d_in[1];
  const int* et = (const int*)d_in[2];
  const float* rel = (const float*)d_in[3];
  const float* wself = (const float*)d_in[4];
  const float* bself = (const float*)d_in[5];
  float* out = (float*)d_out;

  const int N = in_sizes[0] / 128;
  const long E = in_sizes[2];
  const int R = in_sizes[3] / (128 * 128);
  const int NR = R + 1;
  const int* srcp = ei;
  const int* dstp = ei + E;

  // workspace layout (all 256B-aligned)
  size_t off = 0;
  auto alloc = [&](size_t bytes) {
    size_t o = off;
    off += (bytes + 255) & ~(size_t)255;
    return o;
  };
  size_t deg2_off = alloc((size_t)NCLS * N * 4);
  size_t nodedeg_off = alloc((size_t)N * 4);
  size_t nstart_off = alloc((size_t)N * 4);
  size_t cursor_off = alloc((size_t)NCLS * N * 4);
  size_t bsum_off = alloc(4096);
  size_t wT_off = alloc((size_t)NR * 128 * 128 * 2);
  size_t packed_off = alloc((size_t)E * 4);
  size_t xb_off = alloc((size_t)N * 128 * 2);
  size_t S_off = alloc((size_t)N * 8 * 128 * 2);
  const bool main_path = (ws_size >= off) && (N <= 1024 * 1024) && (R == 8);

  if (main_path) {
    int* deg2 = (int*)((char*)d_ws + deg2_off);
    int* nodedeg = (int*)((char*)d_ws + nodedeg_off);
    int* nstart = (int*)((char*)d_ws + nstart_off);
    int* cursor = (int*)((char*)d_ws + cursor_off);
    int* bsum = (int*)((char*)d_ws + bsum_off);
    ushort* wT = (ushort*)((char*)d_ws + wT_off);
    uint* packed = (uint*)((char*)d_ws + packed_off);
    ushort* xb = (ushort*)((char*)d_ws + xb_off);
    ushort* S = (ushort*)((char*)d_ws + S_off);

    hipMemsetAsync(deg2, 0, (size_t)NCLS * N * 4, stream);
    deg2_kernel<<<2048, 256, 0, stream>>>(dstp, deg2, N, E);
    nodedeg_kernel<<<(N + 255) / 256, 256, 0, stream>>>(deg2, nodedeg, N);

    const int nb = (N + 1023) / 1024;
    scan1<<<nb, 256, 0, stream>>>(nodedeg, nstart, bsum, N);
    scan2<<<1, 256, 0, stream>>>(bsum, nb);
    scan3<<<(N + 255) / 256, 256, 0, stream>>>(nstart, bsum, N);
    cursor_init<<<(N + 255) / 256, 256, 0, stream>>>(deg2, nstart, cursor, N);
    fill_csr<<<2048, 256, 0, stream>>>(srcp, dstp, et, cursor, packed, N, E);
    conv_x_kernel<<<2048, 256, 0, stream>>>(x, xb, (long)N * 32);
    build_wT<<<(NR * 16384 + 255) / 256, 256, 0, stream>>>(rel, wself, wT, R);
    gather_sum<<<(N + 3) / 4, 256, 0, stream>>>(packed, nstart, nodedeg, xb, S, N);
    agg_gemm<<<(N + 255) / 256, 512, 0, stream>>>(S, xb, wT, bself, out, N, NR);
  } else {
    int* deg = (int*)((char*)d_ws + deg2_off);
    hipMemsetAsync(deg, 0, (size_t)N * 4, stream);
    deg_kernel<<<2048, 256, 0, stream>>>(dstp, deg, E);
    hipMemsetAsync(out, 0, (size_t)out_size * 4, stream);
    naive_edge<<<4096, 256, 0, stream>>>(x, srcp, dstp, et, rel, out, E);
    naive_self<<<N, 128, 0, stream>>>(x, wself, bself, deg, out, N);
  }
}

// Round 7
// 455.009 us; speedup vs baseline: 1.2383x; 1.0190x over previous
//
#include <hip/hip_runtime.h>
#include <hip/hip_bf16.h>

typedef __attribute__((ext_vector_type(4))) float f32x4_t;
typedef __attribute__((ext_vector_type(8))) short bf16x8_t;

#define NCLS 8  // XCD count / partition classes

__device__ __forceinline__ float bf2f(ushort u) {
  return __uint_as_float(((unsigned)u) << 16);
}
__device__ __forceinline__ ushort f2bf(float f) {
  unsigned u = __float_as_uint(f);
  u += 0x7fffu + ((u >> 16) & 1u);
  return (ushort)(u >> 16);
}
__device__ __forceinline__ uint packbf2(float x, float y) {
  return (uint)f2bf(x) | ((uint)f2bf(y) << 16);
}

// ---- histogram of dst, partitioned by class(i) = (i>>8)&7 (XCD-private) ----
__global__ void deg2_kernel(const int* __restrict__ dst, int* __restrict__ deg2,
                            int N, long E) {
  long i = (long)blockIdx.x * blockDim.x + threadIdx.x;
  long st = (long)gridDim.x * blockDim.x;
  for (; i < E; i += st) {
    int cls = (int)((i >> 8) & (NCLS - 1));
    atomicAdd(&deg2[(size_t)cls * N + dst[i]], 1);
  }
}

// ---- nodedeg[d] = sum_c deg2[c][d] ----
__global__ void nodedeg_kernel(const int* __restrict__ deg2, int* __restrict__ nodedeg, int N) {
  int d = blockIdx.x * 256 + threadIdx.x;
  if (d >= N) return;
  int s = 0;
#pragma unroll
  for (int c = 0; c < NCLS; c++) s += deg2[(size_t)c * N + d];
  nodedeg[d] = s;
}

// ---- generic exclusive scan pieces ----
__global__ __launch_bounds__(256) void scan1(const int* __restrict__ deg, int* __restrict__ starts,
                                             int* __restrict__ bsum, int M) {
  __shared__ int lds[256];
  const int tid = threadIdx.x;
  const int base = blockIdx.x * 1024 + tid * 4;
  int v0 = 0, v1 = 0, v2 = 0, v3 = 0;
  if (base + 3 < M) {
    int4 q = *(const int4*)(deg + base);
    v0 = q.x; v1 = q.y; v2 = q.z; v3 = q.w;
  } else {
    if (base + 0 < M) v0 = deg[base];
    if (base + 1 < M) v1 = deg[base + 1];
    if (base + 2 < M) v2 = deg[base + 2];
    if (base + 3 < M) v3 = deg[base + 3];
  }
  int s = v0 + v1 + v2 + v3;
  lds[tid] = s;
  __syncthreads();
  for (int off = 1; off < 256; off <<= 1) {
    int t = (tid >= off) ? lds[tid - off] : 0;
    __syncthreads();
    lds[tid] += t;
    __syncthreads();
  }
  int p = lds[tid] - s;
  if (tid == 255) bsum[blockIdx.x] = lds[255];
  if (base + 0 < M) starts[base + 0] = p; p += v0;
  if (base + 1 < M) starts[base + 1] = p; p += v1;
  if (base + 2 < M) starts[base + 2] = p; p += v2;
  if (base + 3 < M) starts[base + 3] = p;
}

__global__ __launch_bounds__(256) void scan2(int* __restrict__ bsum, int nb) {
  __shared__ int lds[256];
  const int tid = threadIdx.x;
  const int base = tid * 4;
  int v[4];
#pragma unroll
  for (int j = 0; j < 4; j++) v[j] = (base + j < nb) ? bsum[base + j] : 0;
  int s = v[0] + v[1] + v[2] + v[3];
  lds[tid] = s;
  __syncthreads();
  for (int off = 1; off < 256; off <<= 1) {
    int t = (tid >= off) ? lds[tid - off] : 0;
    __syncthreads();
    lds[tid] += t;
    __syncthreads();
  }
  int p = lds[tid] - s;
#pragma unroll
  for (int j = 0; j < 4; j++) {
    if (base + j < nb) bsum[base + j] = p;
    p += v[j];
  }
}

// scan3m: finalize M-scan, also materialize cursor copy (class-major CSR)
__global__ void scan3m(int* __restrict__ starts, int* __restrict__ cursor,
                       const int* __restrict__ bsum, int M) {
  int i = blockIdx.x * 256 + threadIdx.x;
  if (i < M) {
    int v = starts[i] + bsum[i >> 10];
    starts[i] = v;
    cursor[i] = v;
  }
}

// scan3n: finalize N-scan (node starts only)
__global__ void scan3n(int* __restrict__ starts, const int* __restrict__ bsum, int M) {
  int i = blockIdx.x * 256 + threadIdx.x;
  if (i < M) starts[i] += bsum[i >> 10];
}

// ---- fill CSR into CLASS-major positions: cursor lines and packed lines
// are both XCD-private (class == blockIdx&7 == XCD under round-robin). ----
__global__ void fill_csr(const int* __restrict__ src, const int* __restrict__ dst,
                         const int* __restrict__ et, int* __restrict__ cursor,
                         uint* __restrict__ packed, int N, long E) {
  long i = (long)blockIdx.x * blockDim.x + threadIdx.x;
  long st = (long)gridDim.x * blockDim.x;
  for (; i < E; i += st) {
    int cls = (int)((i >> 8) & (NCLS - 1));
    int pos = atomicAdd(&cursor[(size_t)cls * N + dst[i]], 1);
    packed[pos] = ((uint)src[i] << 4) | (uint)et[i];
  }
}

// ---- reorder: class-major packed -> dst-major packed.
// Within class c, segments are dst-major, so consecutive threads (nodes)
// read adjacent memory; writes are contiguous per node and adjacent across
// nodes -> both sides coalesce. ~13MB total traffic. ----
__global__ void reorder_kernel(const uint* __restrict__ pin, uint* __restrict__ pout,
                               const int* __restrict__ starts2, const int* __restrict__ deg2,
                               const int* __restrict__ node_starts, int N) {
  int d = blockIdx.x * 256 + threadIdx.x;
  if (d >= N) return;
  int run = node_starts[d];
#pragma unroll
  for (int c = 0; c < NCLS; c++) {
    int s = starts2[(size_t)c * N + d];
    int len = deg2[(size_t)c * N + d];
    for (int k = 0; k < len; k++) pout[run + k] = pin[s + k];
    run += len;
  }
}

// ---- wT[r][o][i] = bf16(W[r][i][o]); slot r==R is w_self ----
__global__ void build_wT(const float* __restrict__ rel, const float* __restrict__ wself,
                         ushort* __restrict__ wT, int R) {
  int id = blockIdx.x * blockDim.x + threadIdx.x;
  int total = (R + 1) * 128 * 128;
  if (id >= total) return;
  int r = id >> 14;
  int rem = id & 16383;
  int o = rem >> 7;
  int i = rem & 127;
  float v = (r < R) ? rel[((size_t)r << 14) + (i << 7) + o] : wself[(i << 7) + o];
  wT[id] = f2bf(v);
}

// ---- x (f32) -> compact bf16 xb (26MB, L3-resident) ----
__global__ void conv_x_kernel(const float* __restrict__ x, ushort* __restrict__ xb, long n4) {
  long i = (long)blockIdx.x * blockDim.x + threadIdx.x;
  long st = (long)gridDim.x * blockDim.x;
  for (; i < n4; i += st) {
    float4 v = ((const float4*)x)[i];
    ushort4 o;
    o.x = f2bf(v.x); o.y = f2bf(v.y); o.z = f2bf(v.z); o.w = f2bf(v.w);
    ((ushort4*)xb)[i] = o;
  }
}

// ---- gather_sum: one wave per dst node; ONE contiguous edge run; 4-unroll.
// Sums bf16 xb rows into 8 per-type f32 accs, pre-scales by 1/deg,
// writes S rows 0..7 (bf16, nontemporal). ----
__global__ __launch_bounds__(256) void gather_sum(const uint* __restrict__ packed,
                                                  const int* __restrict__ node_starts,
                                                  const int* __restrict__ nodedeg,
                                                  const ushort* __restrict__ xb,
                                                  ushort* __restrict__ S,
                                                  int N) {
  const int lane = threadIdx.x & 63;
  const int d = blockIdx.x * 4 + (threadIdx.x >> 6);
  if (d >= N) return;

  const int s0 = node_starts[d];
  const int dg = nodedeg[d];
  const int e1 = s0 + dg;

  float a0x = 0, a0y = 0, a1x = 0, a1y = 0, a2x = 0, a2y = 0, a3x = 0, a3y = 0;
  float a4x = 0, a4y = 0, a5x = 0, a5y = 0, a6x = 0, a6y = 0, a7x = 0, a7y = 0;

#define ACCUM(t, vx, vy)                                  \
  switch (t) {                                            \
    case 0: a0x += vx; a0y += vy; break;                  \
    case 1: a1x += vx; a1y += vy; break;                  \
    case 2: a2x += vx; a2y += vy; break;                  \
    case 3: a3x += vx; a3y += vy; break;                  \
    case 4: a4x += vx; a4y += vy; break;                  \
    case 5: a5x += vx; a5y += vy; break;                  \
    case 6: a6x += vx; a6y += vy; break;                  \
    default: a7x += vx; a7y += vy; break;                 \
  }

  int e = s0;
  for (; e + 3 < e1; e += 4) {
    uint r0 = packed[e], r1 = packed[e + 1], r2 = packed[e + 2], r3 = packed[e + 3];
    ushort2 m0 = *(const ushort2*)(xb + (size_t)(r0 >> 4) * 128 + lane * 2);
    ushort2 m1 = *(const ushort2*)(xb + (size_t)(r1 >> 4) * 128 + lane * 2);
    ushort2 m2 = *(const ushort2*)(xb + (size_t)(r2 >> 4) * 128 + lane * 2);
    ushort2 m3 = *(const ushort2*)(xb + (size_t)(r3 >> 4) * 128 + lane * 2);
    int t0 = (int)(r0 & 15u), t1 = (int)(r1 & 15u);
    int t2 = (int)(r2 & 15u), t3 = (int)(r3 & 15u);
    ACCUM(t0, bf2f(m0.x), bf2f(m0.y));
    ACCUM(t1, bf2f(m1.x), bf2f(m1.y));
    ACCUM(t2, bf2f(m2.x), bf2f(m2.y));
    ACCUM(t3, bf2f(m3.x), bf2f(m3.y));
  }
  for (; e < e1; e++) {
    uint r0 = packed[e];
    ushort2 m0 = *(const ushort2*)(xb + (size_t)(r0 >> 4) * 128 + lane * 2);
    int t0 = (int)(r0 & 15u);
    ACCUM(t0, bf2f(m0.x), bf2f(m0.y));
  }
#undef ACCUM

  const float inv = 1.0f / (float)((dg > 1) ? dg : 1);
  uint* Sd = (uint*)(S + (size_t)d * 1024) + lane;  // 8 rows x 128 bf16 per node
  __builtin_nontemporal_store(packbf2(a0x * inv, a0y * inv), Sd + 0 * 64);
  __builtin_nontemporal_store(packbf2(a1x * inv, a1y * inv), Sd + 1 * 64);
  __builtin_nontemporal_store(packbf2(a2x * inv, a2y * inv), Sd + 2 * 64);
  __builtin_nontemporal_store(packbf2(a3x * inv, a3y * inv), Sd + 3 * 64);
  __builtin_nontemporal_store(packbf2(a4x * inv, a4y * inv), Sd + 4 * 64);
  __builtin_nontemporal_store(packbf2(a5x * inv, a5y * inv), Sd + 5 * 64);
  __builtin_nontemporal_store(packbf2(a6x * inv, a6y * inv), Sd + 6 * 64);
  __builtin_nontemporal_store(packbf2(a7x * inv, a7y * inv), Sd + 7 * 64);
}

// ---- agg_gemm: out[d] = relu( sum_{r<8} S[d][r] @ W_r + xb[d] @ W_self + b ).
// 8 waves x 32 nodes = 256 nodes/block; W_r double-buffered in XOR-swizzled
// LDS; acc held across all 9 relations; self fragment read from compact xb. ----
__global__ __launch_bounds__(512) void agg_gemm(const ushort* __restrict__ S,
                                                const ushort* __restrict__ xb,
                                                const ushort* __restrict__ wT,
                                                const float* __restrict__ b,
                                                float* __restrict__ out,
                                                int N, int NR) {
  __shared__ ushort smem[2][16384];  // 2 x 32KB

  const int tid = threadIdx.x;
  const int lane = tid & 63;
  const int wave = tid >> 6;
  const int l15 = lane & 15;
  const int l4 = lane >> 4;
  const int nodebase = blockIdx.x * 256 + wave * 32;

  int nd[2], rd[2];
  nd[0] = nodebase + l15;
  nd[1] = nodebase + 16 + l15;
  rd[0] = (nd[0] < N) ? nd[0] : (N - 1);
  rd[1] = (nd[1] < N) ? nd[1] : (N - 1);

  f32x4_t acc[2][8];
#pragma unroll
  for (int g = 0; g < 2; g++)
#pragma unroll
    for (int nt = 0; nt < 8; nt++) acc[g][nt] = {0.f, 0.f, 0.f, 0.f};

  // prologue: stage W_0 into buf 0
  {
    bf16x8_t sreg[4];
#pragma unroll
    for (int j = 0; j < 4; j++) {
      int c = tid + j * 512;
      sreg[j] = *(const bf16x8_t*)(wT + c * 8);
    }
#pragma unroll
    for (int j = 0; j < 4; j++) {
      int c = tid + j * 512;
      int o = c >> 4;
      int colb = (c & 15) * 16;
      int byte = o * 256 + (colb ^ ((o & 7) << 4));
      *(bf16x8_t*)((char*)smem[0] + byte) = sreg[j];
    }
  }
  __syncthreads();

  for (int r = 0; r < NR; r++) {
    // S-fragments for this relation (self term comes from compact xb)
    bf16x8_t sf[2][4];
#pragma unroll
    for (int g = 0; g < 2; g++) {
      const ushort* srow = (r < NR - 1) ? (S + ((size_t)rd[g] * 8 + r) * 128 + l4 * 8)
                                        : (xb + (size_t)rd[g] * 128 + l4 * 8);
#pragma unroll
      for (int kk = 0; kk < 4; kk++)
        sf[g][kk] = *(const bf16x8_t*)(srow + kk * 32);
    }

    // prefetch next W (T14: issue before MFMA cluster)
    bf16x8_t sreg[4];
    const bool pf = (r + 1 < NR);
    if (pf) {
      const ushort* wsrc = wT + ((size_t)(r + 1) << 14);
#pragma unroll
      for (int j = 0; j < 4; j++) {
        int c = tid + j * 512;
        sreg[j] = *(const bf16x8_t*)(wsrc + c * 8);
      }
    }

    const char* wbuf = (const char*)smem[r & 1];
#pragma unroll
    for (int nt = 0; nt < 8; nt++) {
      bf16x8_t wf[4];
      const int row = nt * 16 + l15;
      const int swz = (row & 7) << 4;
#pragma unroll
      for (int kk = 0; kk < 4; kk++) {
        int colb = l4 * 16 + kk * 64;
        wf[kk] = *(const bf16x8_t*)(wbuf + row * 256 + (colb ^ swz));
      }
#pragma unroll
      for (int g = 0; g < 2; g++)
#pragma unroll
        for (int kk = 0; kk < 4; kk++)
          acc[g][nt] = __builtin_amdgcn_mfma_f32_16x16x32_bf16(wf[kk], sf[g][kk], acc[g][nt], 0, 0, 0);
    }

    if (pf) {
#pragma unroll
      for (int j = 0; j < 4; j++) {
        int c = tid + j * 512;
        int o = c >> 4;
        int colb = (c & 15) * 16;
        int byte = o * 256 + (colb ^ ((o & 7) << 4));
        *(bf16x8_t*)((char*)smem[(r + 1) & 1] + byte) = sreg[j];
      }
    }
    __syncthreads();
  }

  // epilogue: out = relu(acc + b)
#pragma unroll
  for (int g = 0; g < 2; g++) {
    if (nd[g] < N) {
#pragma unroll
      for (int nt = 0; nt < 8; nt++) {
        float4 bv = *(const float4*)(b + nt * 16 + l4 * 4);
        f32x4_t v = acc[g][nt];
        float4 o;
        o.x = fmaxf(v[0] + bv.x, 0.f);
        o.y = fmaxf(v[1] + bv.y, 0.f);
        o.z = fmaxf(v[2] + bv.z, 0.f);
        o.w = fmaxf(v[3] + bv.w, 0.f);
        *(float4*)(out + (size_t)nd[g] * 128 + nt * 16 + l4 * 4) = o;
      }
    }
  }
}

// ---- Fallback (small workspace): naive per-edge f32 GEMV ----
__global__ void deg_kernel(const int* __restrict__ dst, int* __restrict__ deg, long E) {
  long i = (long)blockIdx.x * blockDim.x + threadIdx.x;
  long st = (long)gridDim.x * blockDim.x;
  for (; i < E; i += st) atomicAdd(&deg[dst[i]], 1);
}
__global__ void naive_edge(const float* __restrict__ x, const int* __restrict__ src,
                           const int* __restrict__ dst, const int* __restrict__ et,
                           const float* __restrict__ rel, float* __restrict__ agg, long E) {
  const int lane = threadIdx.x & 63;
  long wid = ((long)blockIdx.x * blockDim.x + threadIdx.x) >> 6;
  long nw = ((long)gridDim.x * blockDim.x) >> 6;
  for (long e = wid; e < E; e += nw) {
    int s = src[e];
    int d = dst[e];
    int t = et[e];
    const float* xs = x + (size_t)s * 128;
    const float* w = rel + (size_t)t * 128 * 128;
    float a0 = 0.f, a1 = 0.f;
    for (int i = 0; i < 128; i++) {
      float xv = xs[i];
      a0 += xv * w[i * 128 + lane];
      a1 += xv * w[i * 128 + lane + 64];
    }
    atomicAdd(agg + (size_t)d * 128 + lane, a0);
    atomicAdd(agg + (size_t)d * 128 + lane + 64, a1);
  }
}
__global__ void naive_self(const float* __restrict__ x, const float* __restrict__ ws,
                           const float* __restrict__ b, const int* __restrict__ deg,
                           float* __restrict__ out, int N) {
  int v = blockIdx.x;
  int o = threadIdx.x;
  if (v >= N) return;
  const float* xv = x + (size_t)v * 128;
  float acc = b[o];
  for (int i = 0; i < 128; i++) acc += xv[i] * ws[i * 128 + o];
  float dg = (float)max(deg[v], 1);
  float val = acc + out[(size_t)v * 128 + o] / dg;
  out[(size_t)v * 128 + o] = fmaxf(val, 0.f);
}

extern "C" void kernel_launch(void* const* d_in, const int* in_sizes, int n_in,
                              void* d_out, int out_size, void* d_ws, size_t ws_size,
                              hipStream_t stream) {
  const float* x = (const float*)d_in[0];
  const int* ei = (const int*)d_in[1];
  const int* et = (const int*)d_in[2];
  const float* rel = (const float*)d_in[3];
  const float* wself = (const float*)d_in[4];
  const float* bself = (const float*)d_in[5];
  float* out = (float*)d_out;

  const int N = in_sizes[0] / 128;
  const long E = in_sizes[2];
  const int R = in_sizes[3] / (128 * 128);
  const int NR = R + 1;
  const int* srcp = ei;
  const int* dstp = ei + E;
  const int M = NCLS * N;

  // workspace layout (all 256B-aligned)
  size_t off = 0;
  auto alloc = [&](size_t bytes) {
    size_t o = off;
    off += (bytes + 255) & ~(size_t)255;
    return o;
  };
  size_t deg2_off = alloc((size_t)M * 4);
  size_t nodedeg_off = alloc((size_t)N * 4);
  size_t nstart_off = alloc((size_t)N * 4);
  size_t starts2_off = alloc((size_t)M * 4);
  size_t cursor2_off = alloc((size_t)M * 4);
  size_t bsum_off = alloc(4096);
  size_t wT_off = alloc((size_t)NR * 128 * 128 * 2);
  size_t pcls_off = alloc((size_t)E * 4);
  size_t packed_off = alloc((size_t)E * 4);
  size_t xb_off = alloc((size_t)N * 128 * 2);
  size_t S_off = alloc((size_t)N * 8 * 128 * 2);
  const bool main_path = (ws_size >= off) && (M <= 1024 * 1024) && (R == 8);

  if (main_path) {
    int* deg2 = (int*)((char*)d_ws + deg2_off);
    int* nodedeg = (int*)((char*)d_ws + nodedeg_off);
    int* nstart = (int*)((char*)d_ws + nstart_off);
    int* starts2 = (int*)((char*)d_ws + starts2_off);
    int* cursor2 = (int*)((char*)d_ws + cursor2_off);
    int* bsum = (int*)((char*)d_ws + bsum_off);
    ushort* wT = (ushort*)((char*)d_ws + wT_off);
    uint* pcls = (uint*)((char*)d_ws + pcls_off);
    uint* packed = (uint*)((char*)d_ws + packed_off);
    ushort* xb = (ushort*)((char*)d_ws + xb_off);
    ushort* S = (ushort*)((char*)d_ws + S_off);

    hipMemsetAsync(deg2, 0, (size_t)M * 4, stream);
    deg2_kernel<<<2048, 256, 0, stream>>>(dstp, deg2, N, E);
    nodedeg_kernel<<<(N + 255) / 256, 256, 0, stream>>>(deg2, nodedeg, N);

    // M-scan (class-major CSR offsets + cursors)
    const int nbM = (M + 1023) / 1024;
    scan1<<<nbM, 256, 0, stream>>>(deg2, starts2, bsum, M);
    scan2<<<1, 256, 0, stream>>>(bsum, nbM);
    scan3m<<<(M + 255) / 256, 256, 0, stream>>>(starts2, cursor2, bsum, M);

    // N-scan (dst-major node starts)
    const int nbN = (N + 1023) / 1024;
    scan1<<<nbN, 256, 0, stream>>>(nodedeg, nstart, bsum, N);
    scan2<<<1, 256, 0, stream>>>(bsum, nbN);
    scan3n<<<(N + 255) / 256, 256, 0, stream>>>(nstart, bsum, N);

    fill_csr<<<2048, 256, 0, stream>>>(srcp, dstp, et, cursor2, pcls, N, E);
    reorder_kernel<<<(N + 255) / 256, 256, 0, stream>>>(pcls, packed, starts2, deg2, nstart, N);

    conv_x_kernel<<<2048, 256, 0, stream>>>(x, xb, (long)N * 32);
    build_wT<<<(NR * 16384 + 255) / 256, 256, 0, stream>>>(rel, wself, wT, R);
    gather_sum<<<(N + 3) / 4, 256, 0, stream>>>(packed, nstart, nodedeg, xb, S, N);
    agg_gemm<<<(N + 255) / 256, 512, 0, stream>>>(S, xb, wT, bself, out, N, NR);
  } else {
    int* deg = (int*)((char*)d_ws + deg2_off);
    hipMemsetAsync(deg, 0, (size_t)N * 4, stream);
    deg_kernel<<<2048, 256, 0, stream>>>(dstp, deg, E);
    hipMemsetAsync(out, 0, (size_t)out_size * 4, stream);
    naive_edge<<<4096, 256, 0, stream>>>(x, srcp, dstp, et, rel, out, E);
    naive_self<<<N, 128, 0, stream>>>(x, wself, bself, deg, out, N);
  }
}

// Round 8
// 437.372 us; speedup vs baseline: 1.2882x; 1.0403x over previous
//
#include <hip/hip_runtime.h>
#include <hip/hip_bf16.h>

typedef __attribute__((ext_vector_type(4))) float f32x4_t;
typedef __attribute__((ext_vector_type(8))) short bf16x8_t;

#define NCLS 8  // XCD count / partition classes

__device__ __forceinline__ float bf2f(ushort u) {
  return __uint_as_float(((unsigned)u) << 16);
}
__device__ __forceinline__ ushort f2bf(float f) {
  unsigned u = __float_as_uint(f);
  u += 0x7fffu + ((u >> 16) & 1u);
  return (ushort)(u >> 16);
}
__device__ __forceinline__ uint packbf2(float x, float y) {
  return (uint)f2bf(x) | ((uint)f2bf(y) << 16);
}

// ---- histogram of dst into class-private rows; class = blockIdx&7 so each
// class's counter lines are touched by exactly one XCD (round-robin). ----
__global__ void deg2_kernel(const int* __restrict__ dst, int* __restrict__ deg2,
                            int N, long E) {
  const int cls = blockIdx.x & (NCLS - 1);
  int* mydeg = deg2 + (size_t)cls * N;
  long q = (long)blockIdx.x * blockDim.x + threadIdx.x;
  const long nq = E >> 2;
  const long st = (long)gridDim.x * blockDim.x;
  for (; q < nq; q += st) {
    int4 d4 = ((const int4*)dst)[q];
    atomicAdd(&mydeg[d4.x], 1);
    atomicAdd(&mydeg[d4.y], 1);
    atomicAdd(&mydeg[d4.z], 1);
    atomicAdd(&mydeg[d4.w], 1);
  }
}

// ---- scan1b: fused first-pass scans.
// Blocks [0,nbM): chunk-scan deg2 (M elems) -> starts2 partials + bsum[0..].
// Blocks [nbM,..): compute nodedeg inline (sum over 8 classes), store it,
// chunk-scan -> nstart partials + bsum[1024..]. ----
__global__ __launch_bounds__(256) void scan1b(const int* __restrict__ deg2,
                                              int* __restrict__ starts2, int* __restrict__ nodedeg,
                                              int* __restrict__ nstart, int* __restrict__ bsum,
                                              int N, int M, int nbM) {
  __shared__ int lds[256];
  const int tid = threadIdx.x;
  int v0 = 0, v1 = 0, v2 = 0, v3 = 0;
  int* outp;
  int* bs;
  int base, lim, bidx;
  if ((int)blockIdx.x < nbM) {
    bidx = blockIdx.x;
    base = bidx * 1024 + tid * 4;
    lim = M;
    if (base + 3 < M) {
      int4 q = *(const int4*)(deg2 + base);
      v0 = q.x; v1 = q.y; v2 = q.z; v3 = q.w;
    } else {
      if (base + 0 < M) v0 = deg2[base];
      if (base + 1 < M) v1 = deg2[base + 1];
      if (base + 2 < M) v2 = deg2[base + 2];
      if (base + 3 < M) v3 = deg2[base + 3];
    }
    outp = starts2;
    bs = bsum;
  } else {
    bidx = blockIdx.x - nbM;
    base = bidx * 1024 + tid * 4;
    lim = N;
    if (base + 3 < N) {
#pragma unroll
      for (int c = 0; c < NCLS; c++) {
        int4 q = *(const int4*)(deg2 + (size_t)c * N + base);
        v0 += q.x; v1 += q.y; v2 += q.z; v3 += q.w;
      }
      *(int4*)(nodedeg + base) = make_int4(v0, v1, v2, v3);
    } else {
      for (int k = 0; k < 4; k++) {
        if (base + k < N) {
          int s = 0;
#pragma unroll
          for (int c = 0; c < NCLS; c++) s += deg2[(size_t)c * N + base + k];
          if (k == 0) v0 = s; else if (k == 1) v1 = s; else if (k == 2) v2 = s; else v3 = s;
          nodedeg[base + k] = s;
        }
      }
    }
    outp = nstart;
    bs = bsum + 1024;
  }
  int s = v0 + v1 + v2 + v3;
  lds[tid] = s;
  __syncthreads();
  for (int off = 1; off < 256; off <<= 1) {
    int t = (tid >= off) ? lds[tid - off] : 0;
    __syncthreads();
    lds[tid] += t;
    __syncthreads();
  }
  int p = lds[tid] - s;
  if (tid == 255) bs[bidx] = lds[255];
  if (base + 0 < lim) outp[base + 0] = p; p += v0;
  if (base + 1 < lim) outp[base + 1] = p; p += v1;
  if (base + 2 < lim) outp[base + 2] = p; p += v2;
  if (base + 3 < lim) outp[base + 3] = p;
}

// ---- scan2b: block 0 scans bsum[0..nbM), block 1 scans bsum[1024..1024+nbN) ----
__global__ __launch_bounds__(256) void scan2b(int* __restrict__ bsum, int nbM, int nbN) {
  __shared__ int lds[256];
  int* b = bsum + blockIdx.x * 1024;
  const int nb = (blockIdx.x == 0) ? nbM : nbN;
  const int tid = threadIdx.x;
  const int base = tid * 4;
  int v[4];
#pragma unroll
  for (int j = 0; j < 4; j++) v[j] = (base + j < nb) ? b[base + j] : 0;
  int s = v[0] + v[1] + v[2] + v[3];
  lds[tid] = s;
  __syncthreads();
  for (int off = 1; off < 256; off <<= 1) {
    int t = (tid >= off) ? lds[tid - off] : 0;
    __syncthreads();
    lds[tid] += t;
    __syncthreads();
  }
  int p = lds[tid] - s;
#pragma unroll
  for (int j = 0; j < 4; j++) {
    if (base + j < nb) b[base + j] = p;
    p += v[j];
  }
}

// ---- scan3b: finalize both scans (+ cursor copy for the M-scan) ----
__global__ void scan3b(int* __restrict__ starts2, int* __restrict__ cursor2,
                       int* __restrict__ nstart, const int* __restrict__ bsum,
                       int M, int N) {
  int i = blockIdx.x * 256 + threadIdx.x;
  if (i < M) {
    int v = starts2[i] + bsum[i >> 10];
    starts2[i] = v;
    cursor2[i] = v;
  } else if (i < M + N) {
    int j = i - M;
    nstart[j] += bsum[1024 + (j >> 10)];
  }
}

// ---- fill CSR into CLASS-major positions (cursor + packed lines XCD-private).
// Same launch geometry / class map as deg2_kernel. ----
__global__ void fill_csr(const int* __restrict__ src, const int* __restrict__ dst,
                         const int* __restrict__ et, int* __restrict__ cursor,
                         uint* __restrict__ packed, int N, long E) {
  const int cls = blockIdx.x & (NCLS - 1);
  int* mycur = cursor + (size_t)cls * N;
  long q = (long)blockIdx.x * blockDim.x + threadIdx.x;
  const long nq = E >> 2;
  const long st = (long)gridDim.x * blockDim.x;
  for (; q < nq; q += st) {
    int4 s4 = ((const int4*)src)[q];
    int4 d4 = ((const int4*)dst)[q];
    int4 t4 = ((const int4*)et)[q];
    int p0 = atomicAdd(&mycur[d4.x], 1);
    packed[p0] = ((uint)s4.x << 4) | (uint)t4.x;
    int p1 = atomicAdd(&mycur[d4.y], 1);
    packed[p1] = ((uint)s4.y << 4) | (uint)t4.y;
    int p2 = atomicAdd(&mycur[d4.z], 1);
    packed[p2] = ((uint)s4.z << 4) | (uint)t4.z;
    int p3 = atomicAdd(&mycur[d4.w], 1);
    packed[p3] = ((uint)s4.w << 4) | (uint)t4.w;
  }
}

// ---- reorder: class-major packed -> dst-major packed (both sides coalesce) ----
__global__ void reorder_kernel(const uint* __restrict__ pin, uint* __restrict__ pout,
                               const int* __restrict__ starts2, const int* __restrict__ deg2,
                               const int* __restrict__ node_starts, int N) {
  int d = blockIdx.x * 256 + threadIdx.x;
  if (d >= N) return;
  int run = node_starts[d];
#pragma unroll
  for (int c = 0; c < NCLS; c++) {
    int s = starts2[(size_t)c * N + d];
    int len = deg2[(size_t)c * N + d];
    for (int k = 0; k < len; k++) pout[run + k] = pin[s + k];
    run += len;
  }
}

// ---- prep: build_wT + conv_x fused (independent elementwise work) ----
__global__ void prep_kernel(const float* __restrict__ rel, const float* __restrict__ wself,
                            ushort* __restrict__ wT, const float* __restrict__ x,
                            ushort* __restrict__ xb, int R, long n4) {
  const long total_wT = (long)(R + 1) * 16384;
  const long total = total_wT + n4;
  long i = (long)blockIdx.x * blockDim.x + threadIdx.x;
  const long st = (long)gridDim.x * blockDim.x;
  for (; i < total; i += st) {
    if (i < total_wT) {
      int id = (int)i;
      int r = id >> 14;
      int rem = id & 16383;
      int o = rem >> 7;
      int ii = rem & 127;
      float v = (r < R) ? rel[((size_t)r << 14) + (ii << 7) + o] : wself[(ii << 7) + o];
      wT[id] = f2bf(v);
    } else {
      long j = i - total_wT;
      float4 v = ((const float4*)x)[j];
      ushort4 o;
      o.x = f2bf(v.x); o.y = f2bf(v.y); o.z = f2bf(v.z); o.w = f2bf(v.w);
      ((ushort4*)xb)[j] = o;
    }
  }
}

// ---- gather_sum: one wave per dst node, contiguous edge run.
// Edge records are scalarized via readlane -> SGPR: row base addresses are
// SALU, row loads use SGPR-base + lane offset, and the per-type ACCUM switch
// becomes scalar branches (off the VALU pipe). 8 row loads in flight. ----
__global__ __launch_bounds__(256) void gather_sum(const uint* __restrict__ packed,
                                                  const int* __restrict__ node_starts,
                                                  const int* __restrict__ nodedeg,
                                                  const ushort* __restrict__ xb,
                                                  ushort* __restrict__ S,
                                                  int N) {
  const int lane = threadIdx.x & 63;
  const int d = blockIdx.x * 4 + (threadIdx.x >> 6);
  if (d >= N) return;

  const int s0 = node_starts[d];
  const int dg = nodedeg[d];
  const int e1 = s0 + dg;
  const int voff = lane * 2;  // ushort offset within a 128-wide row

  float a0x = 0, a0y = 0, a1x = 0, a1y = 0, a2x = 0, a2y = 0, a3x = 0, a3y = 0;
  float a4x = 0, a4y = 0, a5x = 0, a5y = 0, a6x = 0, a6y = 0, a7x = 0, a7y = 0;

#define ROWLOAD(r) (*(const ushort2*)(xb + (size_t)((r) >> 4) * 128 + voff))
#define ACCUM(t, m)                                                       \
  {                                                                       \
    float vx = bf2f((m).x), vy = bf2f((m).y);                             \
    switch (t) {                                                          \
      case 0: a0x += vx; a0y += vy; break;                                \
      case 1: a1x += vx; a1y += vy; break;                                \
      case 2: a2x += vx; a2y += vy; break;                                \
      case 3: a3x += vx; a3y += vy; break;                                \
      case 4: a4x += vx; a4y += vy; break;                                \
      case 5: a5x += vx; a5y += vy; break;                                \
      case 6: a6x += vx; a6y += vy; break;                                \
      default: a7x += vx; a7y += vy; break;                               \
    }                                                                     \
  }

  int e = s0;
#pragma unroll 1
  for (; e + 7 < e1; e += 8) {
    uint v = packed[e + (lane & 7)];
    uint r0 = (uint)__builtin_amdgcn_readlane((int)v, 0);
    uint r1 = (uint)__builtin_amdgcn_readlane((int)v, 1);
    uint r2 = (uint)__builtin_amdgcn_readlane((int)v, 2);
    uint r3 = (uint)__builtin_amdgcn_readlane((int)v, 3);
    uint r4 = (uint)__builtin_amdgcn_readlane((int)v, 4);
    uint r5 = (uint)__builtin_amdgcn_readlane((int)v, 5);
    uint r6 = (uint)__builtin_amdgcn_readlane((int)v, 6);
    uint r7 = (uint)__builtin_amdgcn_readlane((int)v, 7);
    ushort2 m0 = ROWLOAD(r0);
    ushort2 m1 = ROWLOAD(r1);
    ushort2 m2 = ROWLOAD(r2);
    ushort2 m3 = ROWLOAD(r3);
    ushort2 m4 = ROWLOAD(r4);
    ushort2 m5 = ROWLOAD(r5);
    ushort2 m6 = ROWLOAD(r6);
    ushort2 m7 = ROWLOAD(r7);
    ACCUM((int)(r0 & 15u), m0);
    ACCUM((int)(r1 & 15u), m1);
    ACCUM((int)(r2 & 15u), m2);
    ACCUM((int)(r3 & 15u), m3);
    ACCUM((int)(r4 & 15u), m4);
    ACCUM((int)(r5 & 15u), m5);
    ACCUM((int)(r6 & 15u), m6);
    ACCUM((int)(r7 & 15u), m7);
  }
  const int rem = e1 - e;
  if (rem > 0) {
    // over-reads <=7 records past e1 (stays inside d_ws; values unused)
    uint v = packed[e + (lane & 7)];
    uint r0 = (uint)__builtin_amdgcn_readlane((int)v, 0);
    { ushort2 m = ROWLOAD(r0); ACCUM((int)(r0 & 15u), m); }
    if (rem > 1) { uint r = (uint)__builtin_amdgcn_readlane((int)v, 1); ushort2 m = ROWLOAD(r); ACCUM((int)(r & 15u), m); }
    if (rem > 2) { uint r = (uint)__builtin_amdgcn_readlane((int)v, 2); ushort2 m = ROWLOAD(r); ACCUM((int)(r & 15u), m); }
    if (rem > 3) { uint r = (uint)__builtin_amdgcn_readlane((int)v, 3); ushort2 m = ROWLOAD(r); ACCUM((int)(r & 15u), m); }
    if (rem > 4) { uint r = (uint)__builtin_amdgcn_readlane((int)v, 4); ushort2 m = ROWLOAD(r); ACCUM((int)(r & 15u), m); }
    if (rem > 5) { uint r = (uint)__builtin_amdgcn_readlane((int)v, 5); ushort2 m = ROWLOAD(r); ACCUM((int)(r & 15u), m); }
    if (rem > 6) { uint r = (uint)__builtin_amdgcn_readlane((int)v, 6); ushort2 m = ROWLOAD(r); ACCUM((int)(r & 15u), m); }
  }
#undef ROWLOAD
#undef ACCUM

  const float inv = 1.0f / (float)((dg > 1) ? dg : 1);
  uint* Sd = (uint*)(S + (size_t)d * 1024) + lane;  // 8 rows x 128 bf16 per node
  __builtin_nontemporal_store(packbf2(a0x * inv, a0y * inv), Sd + 0 * 64);
  __builtin_nontemporal_store(packbf2(a1x * inv, a1y * inv), Sd + 1 * 64);
  __builtin_nontemporal_store(packbf2(a2x * inv, a2y * inv), Sd + 2 * 64);
  __builtin_nontemporal_store(packbf2(a3x * inv, a3y * inv), Sd + 3 * 64);
  __builtin_nontemporal_store(packbf2(a4x * inv, a4y * inv), Sd + 4 * 64);
  __builtin_nontemporal_store(packbf2(a5x * inv, a5y * inv), Sd + 5 * 64);
  __builtin_nontemporal_store(packbf2(a6x * inv, a6y * inv), Sd + 6 * 64);
  __builtin_nontemporal_store(packbf2(a7x * inv, a7y * inv), Sd + 7 * 64);
}

// ---- agg_gemm: out[d] = relu( sum_{r<8} S[d][r] @ W_r + xb[d] @ W_self + b ).
// 8 waves x 32 nodes = 256 nodes/block; W_r double-buffered in XOR-swizzled
// LDS; acc held across all 9 relations; self fragment read from compact xb. ----
__global__ __launch_bounds__(512) void agg_gemm(const ushort* __restrict__ S,
                                                const ushort* __restrict__ xb,
                                                const ushort* __restrict__ wT,
                                                const float* __restrict__ b,
                                                float* __restrict__ out,
                                                int N, int NR) {
  __shared__ ushort smem[2][16384];  // 2 x 32KB

  const int tid = threadIdx.x;
  const int lane = tid & 63;
  const int wave = tid >> 6;
  const int l15 = lane & 15;
  const int l4 = lane >> 4;
  const int nodebase = blockIdx.x * 256 + wave * 32;

  int nd[2], rd[2];
  nd[0] = nodebase + l15;
  nd[1] = nodebase + 16 + l15;
  rd[0] = (nd[0] < N) ? nd[0] : (N - 1);
  rd[1] = (nd[1] < N) ? nd[1] : (N - 1);

  f32x4_t acc[2][8];
#pragma unroll
  for (int g = 0; g < 2; g++)
#pragma unroll
    for (int nt = 0; nt < 8; nt++) acc[g][nt] = {0.f, 0.f, 0.f, 0.f};

  // prologue: stage W_0 into buf 0
  {
    bf16x8_t sreg[4];
#pragma unroll
    for (int j = 0; j < 4; j++) {
      int c = tid + j * 512;
      sreg[j] = *(const bf16x8_t*)(wT + c * 8);
    }
#pragma unroll
    for (int j = 0; j < 4; j++) {
      int c = tid + j * 512;
      int o = c >> 4;
      int colb = (c & 15) * 16;
      int byte = o * 256 + (colb ^ ((o & 7) << 4));
      *(bf16x8_t*)((char*)smem[0] + byte) = sreg[j];
    }
  }
  __syncthreads();

  for (int r = 0; r < NR; r++) {
    // S-fragments for this relation (self term comes from compact xb)
    bf16x8_t sf[2][4];
#pragma unroll
    for (int g = 0; g < 2; g++) {
      const ushort* srow = (r < NR - 1) ? (S + ((size_t)rd[g] * 8 + r) * 128 + l4 * 8)
                                        : (xb + (size_t)rd[g] * 128 + l4 * 8);
#pragma unroll
      for (int kk = 0; kk < 4; kk++)
        sf[g][kk] = *(const bf16x8_t*)(srow + kk * 32);
    }

    // prefetch next W (T14: issue before MFMA cluster)
    bf16x8_t sreg[4];
    const bool pf = (r + 1 < NR);
    if (pf) {
      const ushort* wsrc = wT + ((size_t)(r + 1) << 14);
#pragma unroll
      for (int j = 0; j < 4; j++) {
        int c = tid + j * 512;
        sreg[j] = *(const bf16x8_t*)(wsrc + c * 8);
      }
    }

    const char* wbuf = (const char*)smem[r & 1];
#pragma unroll
    for (int nt = 0; nt < 8; nt++) {
      bf16x8_t wf[4];
      const int row = nt * 16 + l15;
      const int swz = (row & 7) << 4;
#pragma unroll
      for (int kk = 0; kk < 4; kk++) {
        int colb = l4 * 16 + kk * 64;
        wf[kk] = *(const bf16x8_t*)(wbuf + row * 256 + (colb ^ swz));
      }
#pragma unroll
      for (int g = 0; g < 2; g++)
#pragma unroll
        for (int kk = 0; kk < 4; kk++)
          acc[g][nt] = __builtin_amdgcn_mfma_f32_16x16x32_bf16(wf[kk], sf[g][kk], acc[g][nt], 0, 0, 0);
    }

    if (pf) {
#pragma unroll
      for (int j = 0; j < 4; j++) {
        int c = tid + j * 512;
        int o = c >> 4;
        int colb = (c & 15) * 16;
        int byte = o * 256 + (colb ^ ((o & 7) << 4));
        *(bf16x8_t*)((char*)smem[(r + 1) & 1] + byte) = sreg[j];
      }
    }
    __syncthreads();
  }

  // epilogue: out = relu(acc + b)
#pragma unroll
  for (int g = 0; g < 2; g++) {
    if (nd[g] < N) {
#pragma unroll
      for (int nt = 0; nt < 8; nt++) {
        float4 bv = *(const float4*)(b + nt * 16 + l4 * 4);
        f32x4_t v = acc[g][nt];
        float4 o;
        o.x = fmaxf(v[0] + bv.x, 0.f);
        o.y = fmaxf(v[1] + bv.y, 0.f);
        o.z = fmaxf(v[2] + bv.z, 0.f);
        o.w = fmaxf(v[3] + bv.w, 0.f);
        *(float4*)(out + (size_t)nd[g] * 128 + nt * 16 + l4 * 4) = o;
      }
    }
  }
}

// ---- Fallback (small workspace / odd shapes): naive per-edge f32 GEMV ----
__global__ void deg_kernel(const int* __restrict__ dst, int* __restrict__ deg, long E) {
  long i = (long)blockIdx.x * blockDim.x + threadIdx.x;
  long st = (long)gridDim.x * blockDim.x;
  for (; i < E; i += st) atomicAdd(&deg[dst[i]], 1);
}
__global__ void naive_edge(const float* __restrict__ x, const int* __restrict__ src,
                           const int* __restrict__ dst, const int* __restrict__ et,
                           const float* __restrict__ rel, float* __restrict__ agg, long E) {
  const int lane = threadIdx.x & 63;
  long wid = ((long)blockIdx.x * blockDim.x + threadIdx.x) >> 6;
  long nw = ((long)gridDim.x * blockDim.x) >> 6;
  for (long e = wid; e < E; e += nw) {
    int s = src[e];
    int d = dst[e];
    int t = et[e];
    const float* xs = x + (size_t)s * 128;
    const float* w = rel + (size_t)t * 128 * 128;
    float a0 = 0.f, a1 = 0.f;
    for (int i = 0; i < 128; i++) {
      float xv = xs[i];
      a0 += xv * w[i * 128 + lane];
      a1 += xv * w[i * 128 + lane + 64];
    }
    atomicAdd(agg + (size_t)d * 128 + lane, a0);
    atomicAdd(agg + (size_t)d * 128 + lane + 64, a1);
  }
}
__global__ void naive_self(const float* __restrict__ x, const float* __restrict__ ws,
                           const float* __restrict__ b, const int* __restrict__ deg,
                           float* __restrict__ out, int N) {
  int v = blockIdx.x;
  int o = threadIdx.x;
  if (v >= N) return;
  const float* xv = x + (size_t)v * 128;
  float acc = b[o];
  for (int i = 0; i < 128; i++) acc += xv[i] * ws[i * 128 + o];
  float dg = (float)max(deg[v], 1);
  float val = acc + out[(size_t)v * 128 + o] / dg;
  out[(size_t)v * 128 + o] = fmaxf(val, 0.f);
}

extern "C" void kernel_launch(void* const* d_in, const int* in_sizes, int n_in,
                              void* d_out, int out_size, void* d_ws, size_t ws_size,
                              hipStream_t stream) {
  const float* x = (const float*)d_in[0];
  const int* ei = (const int*)d_in[1];
  const int* et = (const int*)d_in[2];
  const float* rel = (const float*)d_in[3];
  const float* wself = (const float*)d_in[4];
  const float* bself = (const float*)d_in[5];
  float* out = (float*)d_out;

  const int N = in_sizes[0] / 128;
  const long E = in_sizes[2];
  const int R = in_sizes[3] / (128 * 128);
  const int NR = R + 1;
  const int* srcp = ei;
  const int* dstp = ei + E;
  const int M = NCLS * N;

  // workspace layout (all 256B-aligned)
  size_t off = 0;
  auto alloc = [&](size_t bytes) {
    size_t o = off;
    off += (bytes + 255) & ~(size_t)255;
    return o;
  };
  size_t deg2_off = alloc((size_t)M * 4);
  size_t nodedeg_off = alloc((size_t)N * 4);
  size_t nstart_off = alloc((size_t)N * 4);
  size_t starts2_off = alloc((size_t)M * 4);
  size_t cursor2_off = alloc((size_t)M * 4);
  size_t bsum_off = alloc(8192);
  size_t wT_off = alloc((size_t)NR * 128 * 128 * 2);
  size_t pcls_off = alloc((size_t)E * 4);
  size_t packed_off = alloc((size_t)E * 4);
  size_t xb_off = alloc((size_t)N * 128 * 2);
  size_t S_off = alloc((size_t)N * 8 * 128 * 2);
  const bool main_path = (ws_size >= off) && (M <= 1024 * 1024) && (R == 8) &&
                         ((E & 3) == 0) && ((N & 3) == 0);

  if (main_path) {
    int* deg2 = (int*)((char*)d_ws + deg2_off);
    int* nodedeg = (int*)((char*)d_ws + nodedeg_off);
    int* nstart = (int*)((char*)d_ws + nstart_off);
    int* starts2 = (int*)((char*)d_ws + starts2_off);
    int* cursor2 = (int*)((char*)d_ws + cursor2_off);
    int* bsum = (int*)((char*)d_ws + bsum_off);
    ushort* wT = (ushort*)((char*)d_ws + wT_off);
    uint* pcls = (uint*)((char*)d_ws + pcls_off);
    uint* packed = (uint*)((char*)d_ws + packed_off);
    ushort* xb = (ushort*)((char*)d_ws + xb_off);
    ushort* S = (ushort*)((char*)d_ws + S_off);

    hipMemsetAsync(deg2, 0, (size_t)M * 4, stream);
    deg2_kernel<<<2048, 256, 0, stream>>>(dstp, deg2, N, E);

    const int nbM = (M + 1023) / 1024;
    const int nbN = (N + 1023) / 1024;
    scan1b<<<nbM + nbN, 256, 0, stream>>>(deg2, starts2, nodedeg, nstart, bsum, N, M, nbM);
    scan2b<<<2, 256, 0, stream>>>(bsum, nbM, nbN);
    scan3b<<<(M + N + 255) / 256, 256, 0, stream>>>(starts2, cursor2, nstart, bsum, M, N);

    fill_csr<<<2048, 256, 0, stream>>>(srcp, dstp, et, cursor2, pcls, N, E);
    reorder_kernel<<<(N + 255) / 256, 256, 0, stream>>>(pcls, packed, starts2, deg2, nstart, N);
    prep_kernel<<<2048, 256, 0, stream>>>(rel, wself, wT, x, xb, R, (long)N * 32);
    gather_sum<<<(N + 3) / 4, 256, 0, stream>>>(packed, nstart, nodedeg, xb, S, N);
    agg_gemm<<<(N + 255) / 256, 512, 0, stream>>>(S, xb, wT, bself, out, N, NR);
  } else {
    int* deg = (int*)((char*)d_ws + deg2_off);
    hipMemsetAsync(deg, 0, (size_t)N * 4, stream);
    deg_kernel<<<2048, 256, 0, stream>>>(dstp, deg, E);
    hipMemsetAsync(out, 0, (size_t)out_size * 4, stream);
    naive_edge<<<4096, 256, 0, stream>>>(x, srcp, dstp, et, rel, out, E);
    naive_self<<<N, 128, 0, stream>>>(x, wself, bself, deg, out, N);
  }
}